// Round 2
// baseline (92175.104 us; speedup 1.0000x reference)
//
#include <hip/hip_runtime.h>
#include <math.h>

#define Tt  30
#define INP 32
#define HID 64
#define G4  256
#define GRP 32      // sequences per group (4 per thread)
#define NEG 0.2f

__device__ __forceinline__ float sigm(float v) { return 1.f / (1.f + expf(-v)); }

__device__ __forceinline__ void atomicMaxF(float* addr, float v) {
    if (v >= 0.f) atomicMax((int*)addr, __float_as_int(v));
    else          atomicMin((unsigned int*)addr, __float_as_uint(v));
}

// 4 accumulators (4 seqs/thread), literal component indexing ONLY — no (&v.x)[u]!
#define FMA4(w, s0, s1, s2, s3) \
    acc0.x += (w).x*(s0); acc0.y += (w).y*(s0); acc0.z += (w).z*(s0); acc0.w += (w).w*(s0); \
    acc1.x += (w).x*(s1); acc1.y += (w).y*(s1); acc1.z += (w).z*(s1); acc1.w += (w).w*(s1); \
    acc2.x += (w).x*(s2); acc2.y += (w).y*(s2); acc2.z += (w).z*(s2); acc2.w += (w).w*(s2); \
    acc3.x += (w).x*(s3); acc3.y += (w).y*(s3); acc3.z += (w).z*(s3); acc3.w += (w).w*(s3);

// ---------------- LSTM layer 0: input (N,T,32) ----------------
// block = 512 thr; grid-loop over 32-seq groups; thread (sg=tid>>6, k=tid&63)
// owns seqs {sg, sg+8, sg+16, sg+24} of the group, hidden col k (all 4 gates).
__global__ __launch_bounds__(512, 2) void k_lstm0(
    const float* __restrict__ x, const float* __restrict__ Wih, const float* __restrict__ Whh,
    const float* __restrict__ bih, const float* __restrict__ bhh,
    float* __restrict__ hseq, float* __restrict__ hS, float* __restrict__ cS,
    int t0, int tc, int C, int NG)
{
    __shared__ float4 sW[(INP + HID) * 64];   // gate-interleaved: floats [(j*64+kk)*4+g]  (96KB)
    __shared__ float4 sB[64];
    __shared__ float  sX[GRP][INP];
    __shared__ float  sH[GRP][HID];

    const int tid = threadIdx.x;
    const int k   = tid & 63;
    const int sg  = tid >> 6;             // 0..7

    for (int idx = tid; idx < (INP + HID) * G4; idx += 512) {
        int j = idx >> 8, col = idx & 255;
        float v = (j < INP) ? Wih[j * G4 + col] : Whh[(j - INP) * G4 + col];
        ((float*)sW)[(j * 64 + (col & 63)) * 4 + (col >> 6)] = v;
    }
    if (tid < G4) ((float*)sB)[(tid & 63) * 4 + (tid >> 6)] = bih[tid] + bhh[tid];

    for (int g = blockIdx.x; g < NG; g += gridDim.x) {
        const int n0 = g * GRP;
        float c0, c1, c2, c3;
        if (t0 == 0) {
            c0 = c1 = c2 = c3 = 0.f;
            sH[sg][k] = 0.f; sH[sg + 8][k] = 0.f; sH[sg + 16][k] = 0.f; sH[sg + 24][k] = 0.f;
        } else {
            c0 = cS[(size_t)(n0 + sg) * HID + k];
            c1 = cS[(size_t)(n0 + sg + 8) * HID + k];
            c2 = cS[(size_t)(n0 + sg + 16) * HID + k];
            c3 = cS[(size_t)(n0 + sg + 24) * HID + k];
            sH[sg][k]      = hS[(size_t)(n0 + sg) * HID + k];
            sH[sg + 8][k]  = hS[(size_t)(n0 + sg + 8) * HID + k];
            sH[sg + 16][k] = hS[(size_t)(n0 + sg + 16) * HID + k];
            sH[sg + 24][k] = hS[(size_t)(n0 + sg + 24) * HID + k];
        }

        for (int tt = 0; tt < tc; ++tt) {
            const int t = t0 + tt;
            { // stage x_t: 32*32 = 1024 elements
                int idx = tid;            // two strided slots
                int s = idx >> 5, j = idx & 31;
                sX[s][j] = x[(size_t)(n0 + s) * Tt * INP + t * INP + j];
                idx = tid + 512; s = idx >> 5; j = idx & 31;
                sX[s][j] = x[(size_t)(n0 + s) * Tt * INP + t * INP + j];
            }
            __syncthreads();   // publishes sX, sH(prev step / init), sW(first pass)

            float4 acc0 = sB[k], acc1 = acc0, acc2 = acc0, acc3 = acc0;
            #pragma unroll
            for (int j = 0; j < INP; j += 4) {
                float4 x0 = *(const float4*)&sX[sg][j];
                float4 x1 = *(const float4*)&sX[sg + 8][j];
                float4 x2 = *(const float4*)&sX[sg + 16][j];
                float4 x3 = *(const float4*)&sX[sg + 24][j];
                float4 w;
                w = sW[(j + 0) * 64 + k]; FMA4(w, x0.x, x1.x, x2.x, x3.x);
                w = sW[(j + 1) * 64 + k]; FMA4(w, x0.y, x1.y, x2.y, x3.y);
                w = sW[(j + 2) * 64 + k]; FMA4(w, x0.z, x1.z, x2.z, x3.z);
                w = sW[(j + 3) * 64 + k]; FMA4(w, x0.w, x1.w, x2.w, x3.w);
            }
            #pragma unroll
            for (int j = 0; j < HID; j += 4) {
                float4 x0 = *(const float4*)&sH[sg][j];
                float4 x1 = *(const float4*)&sH[sg + 8][j];
                float4 x2 = *(const float4*)&sH[sg + 16][j];
                float4 x3 = *(const float4*)&sH[sg + 24][j];
                float4 w;
                w = sW[(INP + j + 0) * 64 + k]; FMA4(w, x0.x, x1.x, x2.x, x3.x);
                w = sW[(INP + j + 1) * 64 + k]; FMA4(w, x0.y, x1.y, x2.y, x3.y);
                w = sW[(INP + j + 2) * 64 + k]; FMA4(w, x0.z, x1.z, x2.z, x3.z);
                w = sW[(INP + j + 3) * 64 + k]; FMA4(w, x0.w, x1.w, x2.w, x3.w);
            }

            float i0 = sigm(acc0.x), f0 = sigm(acc0.y), g0 = tanhf(acc0.z), o0 = sigm(acc0.w);
            c0 = f0 * c0 + i0 * g0; float h0 = o0 * tanhf(c0);
            float i1 = sigm(acc1.x), f1 = sigm(acc1.y), g1 = tanhf(acc1.z), o1 = sigm(acc1.w);
            c1 = f1 * c1 + i1 * g1; float h1 = o1 * tanhf(c1);
            float i2 = sigm(acc2.x), f2 = sigm(acc2.y), g2 = tanhf(acc2.z), o2 = sigm(acc2.w);
            c2 = f2 * c2 + i2 * g2; float h2 = o2 * tanhf(c2);
            float i3 = sigm(acc3.x), f3 = sigm(acc3.y), g3 = tanhf(acc3.z), o3 = sigm(acc3.w);
            c3 = f3 * c3 + i3 * g3; float h3 = o3 * tanhf(c3);

            __syncthreads();   // all reads of old sH/sX done
            sH[sg][k] = h0; sH[sg + 8][k] = h1; sH[sg + 16][k] = h2; sH[sg + 24][k] = h3;
            hseq[((size_t)(n0 + sg) * C + tt) * HID + k]      = h0;
            hseq[((size_t)(n0 + sg + 8) * C + tt) * HID + k]  = h1;
            hseq[((size_t)(n0 + sg + 16) * C + tt) * HID + k] = h2;
            hseq[((size_t)(n0 + sg + 24) * C + tt) * HID + k] = h3;
        }

        if (t0 + tc < Tt) {
            cS[(size_t)(n0 + sg) * HID + k]      = c0;
            cS[(size_t)(n0 + sg + 8) * HID + k]  = c1;
            cS[(size_t)(n0 + sg + 16) * HID + k] = c2;
            cS[(size_t)(n0 + sg + 24) * HID + k] = c3;
            hS[(size_t)(n0 + sg) * HID + k]      = sH[sg][k];
            hS[(size_t)(n0 + sg + 8) * HID + k]  = sH[sg + 8][k];
            hS[(size_t)(n0 + sg + 16) * HID + k] = sH[sg + 16][k];
            hS[(size_t)(n0 + sg + 24) * HID + k] = sH[sg + 24][k];
        }
        __syncthreads();   // group done before next group's sX/sH overwrite
    }
}

// ---------------- LSTM layer 1: input = layer0 h chunk (N,C,64) ----------------
__global__ __launch_bounds__(512, 2) void k_lstm1(
    const float* __restrict__ hseq, const float* __restrict__ Wih, const float* __restrict__ Whh,
    const float* __restrict__ bih, const float* __restrict__ bhh,
    float* __restrict__ h1last, float* __restrict__ hS, float* __restrict__ cS,
    int t0, int tc, int C, int NG)
{
    __shared__ float4 sW[(HID + HID) * 64];   // 128KB
    __shared__ float4 sB[64];
    __shared__ float  sX[GRP][HID];
    __shared__ float  sH[GRP][HID];

    const int tid = threadIdx.x;
    const int k   = tid & 63;
    const int sg  = tid >> 6;

    for (int idx = tid; idx < (HID + HID) * G4; idx += 512) {
        int j = idx >> 8, col = idx & 255;
        float v = (j < HID) ? Wih[j * G4 + col] : Whh[(j - HID) * G4 + col];
        ((float*)sW)[(j * 64 + (col & 63)) * 4 + (col >> 6)] = v;
    }
    if (tid < G4) ((float*)sB)[(tid & 63) * 4 + (tid >> 6)] = bih[tid] + bhh[tid];

    for (int g = blockIdx.x; g < NG; g += gridDim.x) {
        const int n0 = g * GRP;
        float c0, c1, c2, c3;
        if (t0 == 0) {
            c0 = c1 = c2 = c3 = 0.f;
            sH[sg][k] = 0.f; sH[sg + 8][k] = 0.f; sH[sg + 16][k] = 0.f; sH[sg + 24][k] = 0.f;
        } else {
            c0 = cS[(size_t)(n0 + sg) * HID + k];
            c1 = cS[(size_t)(n0 + sg + 8) * HID + k];
            c2 = cS[(size_t)(n0 + sg + 16) * HID + k];
            c3 = cS[(size_t)(n0 + sg + 24) * HID + k];
            sH[sg][k]      = hS[(size_t)(n0 + sg) * HID + k];
            sH[sg + 8][k]  = hS[(size_t)(n0 + sg + 8) * HID + k];
            sH[sg + 16][k] = hS[(size_t)(n0 + sg + 16) * HID + k];
            sH[sg + 24][k] = hS[(size_t)(n0 + sg + 24) * HID + k];
        }

        for (int tt = 0; tt < tc; ++tt) {
            const int t = t0 + tt;
            {   // stage layer0 h_t: 32*64 = 2048 elements
                int idx = tid;
                int s = idx >> 6, j = idx & 63;
                sX[s][j] = hseq[((size_t)(n0 + s) * C + tt) * HID + j];
                idx = tid + 512;  s = idx >> 6; j = idx & 63;
                sX[s][j] = hseq[((size_t)(n0 + s) * C + tt) * HID + j];
                idx = tid + 1024; s = idx >> 6; j = idx & 63;
                sX[s][j] = hseq[((size_t)(n0 + s) * C + tt) * HID + j];
                idx = tid + 1536; s = idx >> 6; j = idx & 63;
                sX[s][j] = hseq[((size_t)(n0 + s) * C + tt) * HID + j];
            }
            __syncthreads();

            float4 acc0 = sB[k], acc1 = acc0, acc2 = acc0, acc3 = acc0;
            #pragma unroll
            for (int j = 0; j < HID; j += 4) {
                float4 x0 = *(const float4*)&sX[sg][j];
                float4 x1 = *(const float4*)&sX[sg + 8][j];
                float4 x2 = *(const float4*)&sX[sg + 16][j];
                float4 x3 = *(const float4*)&sX[sg + 24][j];
                float4 w;
                w = sW[(j + 0) * 64 + k]; FMA4(w, x0.x, x1.x, x2.x, x3.x);
                w = sW[(j + 1) * 64 + k]; FMA4(w, x0.y, x1.y, x2.y, x3.y);
                w = sW[(j + 2) * 64 + k]; FMA4(w, x0.z, x1.z, x2.z, x3.z);
                w = sW[(j + 3) * 64 + k]; FMA4(w, x0.w, x1.w, x2.w, x3.w);
            }
            #pragma unroll
            for (int j = 0; j < HID; j += 4) {
                float4 x0 = *(const float4*)&sH[sg][j];
                float4 x1 = *(const float4*)&sH[sg + 8][j];
                float4 x2 = *(const float4*)&sH[sg + 16][j];
                float4 x3 = *(const float4*)&sH[sg + 24][j];
                float4 w;
                w = sW[(HID + j + 0) * 64 + k]; FMA4(w, x0.x, x1.x, x2.x, x3.x);
                w = sW[(HID + j + 1) * 64 + k]; FMA4(w, x0.y, x1.y, x2.y, x3.y);
                w = sW[(HID + j + 2) * 64 + k]; FMA4(w, x0.z, x1.z, x2.z, x3.z);
                w = sW[(HID + j + 3) * 64 + k]; FMA4(w, x0.w, x1.w, x2.w, x3.w);
            }

            float i0 = sigm(acc0.x), f0 = sigm(acc0.y), g0 = tanhf(acc0.z), o0 = sigm(acc0.w);
            c0 = f0 * c0 + i0 * g0; float h0 = o0 * tanhf(c0);
            float i1 = sigm(acc1.x), f1 = sigm(acc1.y), g1 = tanhf(acc1.z), o1 = sigm(acc1.w);
            c1 = f1 * c1 + i1 * g1; float h1 = o1 * tanhf(c1);
            float i2 = sigm(acc2.x), f2 = sigm(acc2.y), g2 = tanhf(acc2.z), o2 = sigm(acc2.w);
            c2 = f2 * c2 + i2 * g2; float h2 = o2 * tanhf(c2);
            float i3 = sigm(acc3.x), f3 = sigm(acc3.y), g3 = tanhf(acc3.z), o3 = sigm(acc3.w);
            c3 = f3 * c3 + i3 * g3; float h3 = o3 * tanhf(c3);

            __syncthreads();
            sH[sg][k] = h0; sH[sg + 8][k] = h1; sH[sg + 16][k] = h2; sH[sg + 24][k] = h3;
            if (t == Tt - 1) {
                h1last[(size_t)(n0 + sg) * HID + k]      = h0;
                h1last[(size_t)(n0 + sg + 8) * HID + k]  = h1;
                h1last[(size_t)(n0 + sg + 16) * HID + k] = h2;
                h1last[(size_t)(n0 + sg + 24) * HID + k] = h3;
            }
        }

        if (t0 + tc < Tt) {
            cS[(size_t)(n0 + sg) * HID + k]      = c0;
            cS[(size_t)(n0 + sg + 8) * HID + k]  = c1;
            cS[(size_t)(n0 + sg + 16) * HID + k] = c2;
            cS[(size_t)(n0 + sg + 24) * HID + k] = c3;
            hS[(size_t)(n0 + sg) * HID + k]      = sH[sg][k];
            hS[(size_t)(n0 + sg + 8) * HID + k]  = sH[sg + 8][k];
            hS[(size_t)(n0 + sg + 16) * HID + k] = sH[sg + 16][k];
            hS[(size_t)(n0 + sg + 24) * HID + k] = sH[sg + 24][k];
        }
        __syncthreads();
    }
}

// ---------------- GAT1 projection: H1 = h @ W1 ; a_src/a_dst per head ----------------
__global__ __launch_bounds__(256) void k_gproj1(
    const float* __restrict__ hl, const float* __restrict__ W1,
    const float* __restrict__ as1, const float* __restrict__ ad1,
    float* __restrict__ H1, float* __restrict__ a_s, float* __restrict__ a_d)
{
    __shared__ float sh[64];
    const int n = blockIdx.x, tid = threadIdx.x;
    if (tid < 64) sh[tid] = hl[(size_t)n * 64 + tid];
    __syncthreads();
    float acc = 0.f;
    #pragma unroll
    for (int j = 0; j < 64; ++j) acc += sh[j] * W1[j * 256 + tid];
    H1[(size_t)n * 256 + tid] = acc;
    float ls = acc * as1[tid], ld = acc * ad1[tid];
    #pragma unroll
    for (int off = 32; off >= 1; off >>= 1) { ls += __shfl_down(ls, off); ld += __shfl_down(ld, off); }
    if ((tid & 63) == 0) { a_s[n * 4 + (tid >> 6)] = ls; a_d[n * 4 + (tid >> 6)] = ld; }
}

// ---------------- edge max (4 heads) ----------------
__global__ void k_emax1(const int* __restrict__ ei, const float* __restrict__ a_s,
                        const float* __restrict__ a_d, float* __restrict__ m, int E, int Et)
{
    int idx = blockIdx.x * blockDim.x + threadIdx.x;
    if (idx >= Et * 4) return;
    int e = idx >> 2, h = idx & 3;
    int s, d;
    if (e < E) { s = ei[e]; d = ei[E + e]; } else { s = d = e - E; }
    float a = a_s[s * 4 + h] + a_d[d * 4 + h];
    float l = a > 0.f ? a : NEG * a;
    atomicMaxF(&m[d * 4 + h], l);
}

// ---------------- edge scatter (4 heads x 64) ----------------
__global__ __launch_bounds__(256) void k_escat1(
    const int* __restrict__ ei, const float* __restrict__ a_s, const float* __restrict__ a_d,
    const float* __restrict__ m, float* __restrict__ ssum,
    const float* __restrict__ H1, float* __restrict__ un, int E, int Et)
{
    int e = blockIdx.x;
    int tid = threadIdx.x, h = tid >> 6;
    int s, d;
    if (e < E) { s = ei[e]; d = ei[E + e]; } else { s = d = e - E; }
    float a = a_s[s * 4 + h] + a_d[d * 4 + h];
    float l = a > 0.f ? a : NEG * a;
    float ev = expf(l - m[d * 4 + h]);
    if ((tid & 63) == 0) atomicAdd(&ssum[d * 4 + h], ev);
    atomicAdd(&un[(size_t)d * 256 + tid], ev * H1[(size_t)s * 256 + tid]);
}

// ---------------- GAT1 finalize: /sum + bias + relu (in place -> h2) ----------------
__global__ void k_efin1(float* __restrict__ un, const float* __restrict__ ssum,
                        const float* __restrict__ b1, int N)
{
    int idx = blockIdx.x * blockDim.x + threadIdx.x;
    if (idx >= N * 256) return;
    int n = idx >> 8, k = idx & 255, h = k >> 6;
    float v = un[idx] / ssum[n * 4 + h] + b1[k];
    un[idx] = v > 0.f ? v : 0.f;
}

// ---------------- GAT2 projection ----------------
__global__ __launch_bounds__(256) void k_gproj2(
    const float* __restrict__ h2, const float* __restrict__ W2,
    const float* __restrict__ as2, const float* __restrict__ ad2,
    float* __restrict__ H2, float* __restrict__ a2s, float* __restrict__ a2d)
{
    __shared__ float sh2[4][256];
    const int tid = threadIdx.x;
    const int n0 = blockIdx.x * 4;
    for (int idx = tid; idx < 1024; idx += 256)
        sh2[idx >> 8][idx & 255] = h2[(size_t)(n0 + (idx >> 8)) * 256 + (idx & 255)];
    __syncthreads();
    int w = tid >> 6, L = tid & 63, c = L & 31, half = L >> 5;
    float acc = 0.f;
    #pragma unroll
    for (int j = 0; j < 128; ++j) acc += sh2[w][half * 128 + j] * W2[(half * 128 + j) * 32 + c];
    acc += __shfl_down(acc, 32);
    float ls = 0.f, ld = 0.f;
    if (L < 32) {
        H2[(size_t)(n0 + w) * 32 + c] = acc;
        ls = acc * as2[c]; ld = acc * ad2[c];
    }
    #pragma unroll
    for (int off = 16; off >= 1; off >>= 1) { ls += __shfl_down(ls, off); ld += __shfl_down(ld, off); }
    if (L == 0) { a2s[n0 + w] = ls; a2d[n0 + w] = ld; }
}

// ---------------- edge max (1 head) ----------------
__global__ void k_emax2(const int* __restrict__ ei, const float* __restrict__ a_s,
                        const float* __restrict__ a_d, float* __restrict__ m, int E, int Et)
{
    int e = blockIdx.x * blockDim.x + threadIdx.x;
    if (e >= Et) return;
    int s, d;
    if (e < E) { s = ei[e]; d = ei[E + e]; } else { s = d = e - E; }
    float a = a_s[s] + a_d[d];
    float l = a > 0.f ? a : NEG * a;
    atomicMaxF(&m[d], l);
}

// ---------------- edge scatter (32 cols) into d_out ----------------
__global__ __launch_bounds__(256) void k_escat2(
    const int* __restrict__ ei, const float* __restrict__ a_s, const float* __restrict__ a_d,
    const float* __restrict__ m, float* __restrict__ ssum,
    const float* __restrict__ H2, float* __restrict__ outp, int E, int Et)
{
    int idx = blockIdx.x * blockDim.x + threadIdx.x;
    if (idx >= Et * 32) return;
    int e = idx >> 5, c = idx & 31;
    int s, d;
    if (e < E) { s = ei[e]; d = ei[E + e]; } else { s = d = e - E; }
    float a = a_s[s] + a_d[d];
    float l = a > 0.f ? a : NEG * a;
    float ev = expf(l - m[d]);
    if (c == 0) atomicAdd(&ssum[d], ev);
    atomicAdd(&outp[(size_t)d * 32 + c], ev * H2[(size_t)s * 32 + c]);
}

// ---------------- GAT2 finalize ----------------
__global__ void k_efin2(float* __restrict__ outp, const float* __restrict__ ssum,
                        const float* __restrict__ b2, int N)
{
    int idx = blockIdx.x * blockDim.x + threadIdx.x;
    if (idx >= N * 32) return;
    outp[idx] = outp[idx] / ssum[idx >> 5] + b2[idx & 31];
}

__global__ void k_neginf(float* __restrict__ p, int n)
{
    int idx = blockIdx.x * blockDim.x + threadIdx.x;
    if (idx < n) p[idx] = -INFINITY;
}

static inline int cdiv(long long a, long long b) { return (int)((a + b - 1) / b); }

extern "C" void kernel_launch(void* const* d_in, const int* in_sizes, int n_in,
                              void* d_out, int out_size, void* d_ws, size_t ws_size,
                              hipStream_t stream)
{
    const float* x    = (const float*)d_in[0];
    const int*   ei   = (const int*)d_in[1];
    const float* Wih0 = (const float*)d_in[2];
    const float* Whh0 = (const float*)d_in[3];
    const float* bih0 = (const float*)d_in[4];
    const float* bhh0 = (const float*)d_in[5];
    const float* Wih1 = (const float*)d_in[6];
    const float* Whh1 = (const float*)d_in[7];
    const float* bih1 = (const float*)d_in[8];
    const float* bhh1 = (const float*)d_in[9];
    const float* W1   = (const float*)d_in[10];
    const float* as1  = (const float*)d_in[11];
    const float* ad1  = (const float*)d_in[12];
    const float* b1   = (const float*)d_in[13];
    const float* W2   = (const float*)d_in[14];
    const float* as2  = (const float*)d_in[15];
    const float* ad2  = (const float*)d_in[16];
    const float* b2   = (const float*)d_in[17];
    float* outp = (float*)d_out;

    const int N  = in_sizes[0] / (Tt * INP);
    const int E  = in_sizes[1] / 2;
    const int Et = E + N;
    const int NG = N / GRP;                 // 32-seq groups

    float* ws = (float*)d_ws;
    const size_t N64 = (size_t)N * 64;

    float* h1last = ws;               // N*64, persists LSTM -> GAT
    float* rA = ws + N64;

    // region A (LSTM)
    float* h0s = rA;
    float* c0s = rA + N64;
    float* h1s = rA + 2 * N64;
    float* c1s = rA + 3 * N64;
    float* h0chunk = rA + 4 * N64;    // N*C*64

    long long availChunkRows = (long long)(ws_size / 4) - (long long)(5 * N64);
    int C = (int)(availChunkRows / (long long)N64);
    if (C > Tt) C = Tt;
    if (C < 1) C = 1;

    // region B (GAT) — overlays region A
    float* H1   = rA;                         // N*256
    float* un1  = H1 + (size_t)N * 256;       // N*256 (becomes h2)
    float* H2   = un1 + (size_t)N * 256;      // N*32
    float* as1p = H2 + (size_t)N * 32;        // N*4
    float* ad1p = as1p + (size_t)N * 4;
    float* m1   = ad1p + (size_t)N * 4;
    float* s1   = m1 + (size_t)N * 4;
    float* a2s  = s1 + (size_t)N * 4;         // N
    float* a2d  = a2s + N;
    float* m2   = a2d + N;
    float* s2   = m2 + N;

    // ---- LSTM (chunked over T; persistent-ish grid: 256 blocks, 1/CU by LDS) ----
    for (int t0 = 0; t0 < Tt; t0 += C) {
        int tc = Tt - t0 < C ? Tt - t0 : C;
        k_lstm0<<<dim3(256), dim3(512), 0, stream>>>(x, Wih0, Whh0, bih0, bhh0,
                                                     h0chunk, h0s, c0s, t0, tc, C, NG);
        k_lstm1<<<dim3(256), dim3(512), 0, stream>>>(h0chunk, Wih1, Whh1, bih1, bhh1,
                                                     h1last, h1s, c1s, t0, tc, C, NG);
    }

    // ---- init GAT accumulators ----
    hipMemsetAsync(un1, 0, (size_t)N * 256 * 4, stream);
    hipMemsetAsync(s1, 0, (size_t)N * 4 * 4, stream);
    hipMemsetAsync(s2, 0, (size_t)N * 4, stream);
    hipMemsetAsync(outp, 0, (size_t)N * 32 * 4, stream);
    k_neginf<<<cdiv((long long)N * 4, 256), 256, 0, stream>>>(m1, N * 4);
    k_neginf<<<cdiv(N, 256), 256, 0, stream>>>(m2, N);

    // ---- GAT layer 1 ----
    k_gproj1<<<dim3(N), dim3(256), 0, stream>>>(h1last, W1, as1, ad1, H1, as1p, ad1p);
    k_emax1<<<cdiv((long long)Et * 4, 256), 256, 0, stream>>>(ei, as1p, ad1p, m1, E, Et);
    k_escat1<<<dim3(Et), dim3(256), 0, stream>>>(ei, as1p, ad1p, m1, s1, H1, un1, E, Et);
    k_efin1<<<cdiv((long long)N * 256, 256), 256, 0, stream>>>(un1, s1, b1, N);

    // ---- GAT layer 2 ----
    k_gproj2<<<dim3(N / 4), dim3(256), 0, stream>>>(un1, W2, as2, ad2, H2, a2s, a2d);
    k_emax2<<<cdiv(Et, 256), 256, 0, stream>>>(ei, a2s, a2d, m2, E, Et);
    k_escat2<<<cdiv((long long)Et * 32, 256), 256, 0, stream>>>(ei, a2s, a2d, m2, s2, H2, outp, E, Et);
    k_efin2<<<cdiv((long long)N * 32, 256), 256, 0, stream>>>(outp, s2, b2, N);
}

// Round 3
// 2027.933 us; speedup vs baseline: 45.4527x; 45.4527x over previous
//
#include <hip/hip_runtime.h>
#include <math.h>

#define Tt  30
#define INP 32
#define HID 64
#define G4  256
#define GRP 32      // sequences per group (4 per thread)
#define NEG 0.2f

__device__ __forceinline__ float sigm(float v) { return 1.f / (1.f + expf(-v)); }

__device__ __forceinline__ void atomicMaxF(float* addr, float v) {
    if (v >= 0.f) atomicMax((int*)addr, __float_as_int(v));
    else          atomicMin((unsigned int*)addr, __float_as_uint(v));
}

// 4 accumulators (4 seqs/thread), literal component indexing ONLY — no (&v.x)[u]!
#define FMA4(w, s0, s1, s2, s3) \
    acc0.x += (w).x*(s0); acc0.y += (w).y*(s0); acc0.z += (w).z*(s0); acc0.w += (w).w*(s0); \
    acc1.x += (w).x*(s1); acc1.y += (w).y*(s1); acc1.z += (w).z*(s1); acc1.w += (w).w*(s1); \
    acc2.x += (w).x*(s2); acc2.y += (w).y*(s2); acc2.z += (w).z*(s2); acc2.w += (w).w*(s2); \
    acc3.x += (w).x*(s3); acc3.y += (w).y*(s3); acc3.z += (w).z*(s3); acc3.w += (w).w*(s3);

// ---------------- LSTM layer 0: input (N,T,32) ----------------
// block = 512 thr; grid-loop over 32-seq groups; thread (sg=tid>>6, k=tid&63)
// owns seqs {sg, sg+8, sg+16, sg+24} of the group, hidden col k (all 4 gates).
// NOTE: j-loops carry `#pragma unroll 2` — full unroll caused VGPR live-set
// explosion -> scratch spill -> ~100 GB/dispatch of HBM traffic (rounds 1-2).
__global__ __launch_bounds__(512, 2) void k_lstm0(
    const float* __restrict__ x, const float* __restrict__ Wih, const float* __restrict__ Whh,
    const float* __restrict__ bih, const float* __restrict__ bhh,
    float* __restrict__ hseq, float* __restrict__ hS, float* __restrict__ cS,
    int t0, int tc, int C, int NG)
{
    __shared__ float4 sW[(INP + HID) * 64];   // gate-interleaved: floats [(j*64+kk)*4+g]  (96KB)
    __shared__ float4 sB[64];
    __shared__ float  sX[GRP][INP];
    __shared__ float  sH[GRP][HID];

    const int tid = threadIdx.x;
    const int k   = tid & 63;
    const int sg  = tid >> 6;             // 0..7

    for (int idx = tid; idx < (INP + HID) * G4; idx += 512) {
        int j = idx >> 8, col = idx & 255;
        float v = (j < INP) ? Wih[j * G4 + col] : Whh[(j - INP) * G4 + col];
        ((float*)sW)[(j * 64 + (col & 63)) * 4 + (col >> 6)] = v;
    }
    if (tid < G4) ((float*)sB)[(tid & 63) * 4 + (tid >> 6)] = bih[tid] + bhh[tid];

    for (int g = blockIdx.x; g < NG; g += gridDim.x) {
        const int n0 = g * GRP;
        float c0, c1, c2, c3;
        if (t0 == 0) {
            c0 = c1 = c2 = c3 = 0.f;
            sH[sg][k] = 0.f; sH[sg + 8][k] = 0.f; sH[sg + 16][k] = 0.f; sH[sg + 24][k] = 0.f;
        } else {
            c0 = cS[(size_t)(n0 + sg) * HID + k];
            c1 = cS[(size_t)(n0 + sg + 8) * HID + k];
            c2 = cS[(size_t)(n0 + sg + 16) * HID + k];
            c3 = cS[(size_t)(n0 + sg + 24) * HID + k];
            sH[sg][k]      = hS[(size_t)(n0 + sg) * HID + k];
            sH[sg + 8][k]  = hS[(size_t)(n0 + sg + 8) * HID + k];
            sH[sg + 16][k] = hS[(size_t)(n0 + sg + 16) * HID + k];
            sH[sg + 24][k] = hS[(size_t)(n0 + sg + 24) * HID + k];
        }

        for (int tt = 0; tt < tc; ++tt) {
            const int t = t0 + tt;
            { // stage x_t: 32*32 = 1024 elements
                int idx = tid;
                int s = idx >> 5, j = idx & 31;
                sX[s][j] = x[(size_t)(n0 + s) * Tt * INP + t * INP + j];
                idx = tid + 512; s = idx >> 5; j = idx & 31;
                sX[s][j] = x[(size_t)(n0 + s) * Tt * INP + t * INP + j];
            }
            __syncthreads();   // publishes sX, sH(prev step / init), sW(first pass)

            float4 acc0 = sB[k], acc1 = acc0, acc2 = acc0, acc3 = acc0;
            #pragma unroll 2
            for (int j = 0; j < INP; j += 4) {
                float4 x0 = *(const float4*)&sX[sg][j];
                float4 x1 = *(const float4*)&sX[sg + 8][j];
                float4 x2 = *(const float4*)&sX[sg + 16][j];
                float4 x3 = *(const float4*)&sX[sg + 24][j];
                float4 w;
                w = sW[(j + 0) * 64 + k]; FMA4(w, x0.x, x1.x, x2.x, x3.x);
                w = sW[(j + 1) * 64 + k]; FMA4(w, x0.y, x1.y, x2.y, x3.y);
                w = sW[(j + 2) * 64 + k]; FMA4(w, x0.z, x1.z, x2.z, x3.z);
                w = sW[(j + 3) * 64 + k]; FMA4(w, x0.w, x1.w, x2.w, x3.w);
            }
            #pragma unroll 2
            for (int j = 0; j < HID; j += 4) {
                float4 x0 = *(const float4*)&sH[sg][j];
                float4 x1 = *(const float4*)&sH[sg + 8][j];
                float4 x2 = *(const float4*)&sH[sg + 16][j];
                float4 x3 = *(const float4*)&sH[sg + 24][j];
                float4 w;
                w = sW[(INP + j + 0) * 64 + k]; FMA4(w, x0.x, x1.x, x2.x, x3.x);
                w = sW[(INP + j + 1) * 64 + k]; FMA4(w, x0.y, x1.y, x2.y, x3.y);
                w = sW[(INP + j + 2) * 64 + k]; FMA4(w, x0.z, x1.z, x2.z, x3.z);
                w = sW[(INP + j + 3) * 64 + k]; FMA4(w, x0.w, x1.w, x2.w, x3.w);
            }

            float i0 = sigm(acc0.x), f0 = sigm(acc0.y), g0 = tanhf(acc0.z), o0 = sigm(acc0.w);
            c0 = f0 * c0 + i0 * g0; float h0 = o0 * tanhf(c0);
            float i1 = sigm(acc1.x), f1 = sigm(acc1.y), g1 = tanhf(acc1.z), o1 = sigm(acc1.w);
            c1 = f1 * c1 + i1 * g1; float h1 = o1 * tanhf(c1);
            float i2 = sigm(acc2.x), f2 = sigm(acc2.y), g2 = tanhf(acc2.z), o2 = sigm(acc2.w);
            c2 = f2 * c2 + i2 * g2; float h2 = o2 * tanhf(c2);
            float i3 = sigm(acc3.x), f3 = sigm(acc3.y), g3 = tanhf(acc3.z), o3 = sigm(acc3.w);
            c3 = f3 * c3 + i3 * g3; float h3 = o3 * tanhf(c3);

            __syncthreads();   // all reads of old sH/sX done
            sH[sg][k] = h0; sH[sg + 8][k] = h1; sH[sg + 16][k] = h2; sH[sg + 24][k] = h3;
            hseq[((size_t)(n0 + sg) * C + tt) * HID + k]      = h0;
            hseq[((size_t)(n0 + sg + 8) * C + tt) * HID + k]  = h1;
            hseq[((size_t)(n0 + sg + 16) * C + tt) * HID + k] = h2;
            hseq[((size_t)(n0 + sg + 24) * C + tt) * HID + k] = h3;
        }

        if (t0 + tc < Tt) {
            cS[(size_t)(n0 + sg) * HID + k]      = c0;
            cS[(size_t)(n0 + sg + 8) * HID + k]  = c1;
            cS[(size_t)(n0 + sg + 16) * HID + k] = c2;
            cS[(size_t)(n0 + sg + 24) * HID + k] = c3;
            hS[(size_t)(n0 + sg) * HID + k]      = sH[sg][k];
            hS[(size_t)(n0 + sg + 8) * HID + k]  = sH[sg + 8][k];
            hS[(size_t)(n0 + sg + 16) * HID + k] = sH[sg + 16][k];
            hS[(size_t)(n0 + sg + 24) * HID + k] = sH[sg + 24][k];
        }
        __syncthreads();   // group done before next group's sX/sH overwrite
    }
}

// ---------------- LSTM layer 1: input = layer0 h chunk (N,C,64) ----------------
__global__ __launch_bounds__(512, 2) void k_lstm1(
    const float* __restrict__ hseq, const float* __restrict__ Wih, const float* __restrict__ Whh,
    const float* __restrict__ bih, const float* __restrict__ bhh,
    float* __restrict__ h1last, float* __restrict__ hS, float* __restrict__ cS,
    int t0, int tc, int C, int NG)
{
    __shared__ float4 sW[(HID + HID) * 64];   // 128KB
    __shared__ float4 sB[64];
    __shared__ float  sX[GRP][HID];
    __shared__ float  sH[GRP][HID];

    const int tid = threadIdx.x;
    const int k   = tid & 63;
    const int sg  = tid >> 6;

    for (int idx = tid; idx < (HID + HID) * G4; idx += 512) {
        int j = idx >> 8, col = idx & 255;
        float v = (j < HID) ? Wih[j * G4 + col] : Whh[(j - HID) * G4 + col];
        ((float*)sW)[(j * 64 + (col & 63)) * 4 + (col >> 6)] = v;
    }
    if (tid < G4) ((float*)sB)[(tid & 63) * 4 + (tid >> 6)] = bih[tid] + bhh[tid];

    for (int g = blockIdx.x; g < NG; g += gridDim.x) {
        const int n0 = g * GRP;
        float c0, c1, c2, c3;
        if (t0 == 0) {
            c0 = c1 = c2 = c3 = 0.f;
            sH[sg][k] = 0.f; sH[sg + 8][k] = 0.f; sH[sg + 16][k] = 0.f; sH[sg + 24][k] = 0.f;
        } else {
            c0 = cS[(size_t)(n0 + sg) * HID + k];
            c1 = cS[(size_t)(n0 + sg + 8) * HID + k];
            c2 = cS[(size_t)(n0 + sg + 16) * HID + k];
            c3 = cS[(size_t)(n0 + sg + 24) * HID + k];
            sH[sg][k]      = hS[(size_t)(n0 + sg) * HID + k];
            sH[sg + 8][k]  = hS[(size_t)(n0 + sg + 8) * HID + k];
            sH[sg + 16][k] = hS[(size_t)(n0 + sg + 16) * HID + k];
            sH[sg + 24][k] = hS[(size_t)(n0 + sg + 24) * HID + k];
        }

        for (int tt = 0; tt < tc; ++tt) {
            const int t = t0 + tt;
            {   // stage layer0 h_t: 32*64 = 2048 elements
                int idx = tid;
                int s = idx >> 6, j = idx & 63;
                sX[s][j] = hseq[((size_t)(n0 + s) * C + tt) * HID + j];
                idx = tid + 512;  s = idx >> 6; j = idx & 63;
                sX[s][j] = hseq[((size_t)(n0 + s) * C + tt) * HID + j];
                idx = tid + 1024; s = idx >> 6; j = idx & 63;
                sX[s][j] = hseq[((size_t)(n0 + s) * C + tt) * HID + j];
                idx = tid + 1536; s = idx >> 6; j = idx & 63;
                sX[s][j] = hseq[((size_t)(n0 + s) * C + tt) * HID + j];
            }
            __syncthreads();

            float4 acc0 = sB[k], acc1 = acc0, acc2 = acc0, acc3 = acc0;
            #pragma unroll 2
            for (int j = 0; j < HID; j += 4) {
                float4 x0 = *(const float4*)&sX[sg][j];
                float4 x1 = *(const float4*)&sX[sg + 8][j];
                float4 x2 = *(const float4*)&sX[sg + 16][j];
                float4 x3 = *(const float4*)&sX[sg + 24][j];
                float4 w;
                w = sW[(j + 0) * 64 + k]; FMA4(w, x0.x, x1.x, x2.x, x3.x);
                w = sW[(j + 1) * 64 + k]; FMA4(w, x0.y, x1.y, x2.y, x3.y);
                w = sW[(j + 2) * 64 + k]; FMA4(w, x0.z, x1.z, x2.z, x3.z);
                w = sW[(j + 3) * 64 + k]; FMA4(w, x0.w, x1.w, x2.w, x3.w);
            }
            #pragma unroll 2
            for (int j = 0; j < HID; j += 4) {
                float4 x0 = *(const float4*)&sH[sg][j];
                float4 x1 = *(const float4*)&sH[sg + 8][j];
                float4 x2 = *(const float4*)&sH[sg + 16][j];
                float4 x3 = *(const float4*)&sH[sg + 24][j];
                float4 w;
                w = sW[(HID + j + 0) * 64 + k]; FMA4(w, x0.x, x1.x, x2.x, x3.x);
                w = sW[(HID + j + 1) * 64 + k]; FMA4(w, x0.y, x1.y, x2.y, x3.y);
                w = sW[(HID + j + 2) * 64 + k]; FMA4(w, x0.z, x1.z, x2.z, x3.z);
                w = sW[(HID + j + 3) * 64 + k]; FMA4(w, x0.w, x1.w, x2.w, x3.w);
            }

            float i0 = sigm(acc0.x), f0 = sigm(acc0.y), g0 = tanhf(acc0.z), o0 = sigm(acc0.w);
            c0 = f0 * c0 + i0 * g0; float h0 = o0 * tanhf(c0);
            float i1 = sigm(acc1.x), f1 = sigm(acc1.y), g1 = tanhf(acc1.z), o1 = sigm(acc1.w);
            c1 = f1 * c1 + i1 * g1; float h1 = o1 * tanhf(c1);
            float i2 = sigm(acc2.x), f2 = sigm(acc2.y), g2 = tanhf(acc2.z), o2 = sigm(acc2.w);
            c2 = f2 * c2 + i2 * g2; float h2 = o2 * tanhf(c2);
            float i3 = sigm(acc3.x), f3 = sigm(acc3.y), g3 = tanhf(acc3.z), o3 = sigm(acc3.w);
            c3 = f3 * c3 + i3 * g3; float h3 = o3 * tanhf(c3);

            __syncthreads();
            sH[sg][k] = h0; sH[sg + 8][k] = h1; sH[sg + 16][k] = h2; sH[sg + 24][k] = h3;
            if (t == Tt - 1) {
                h1last[(size_t)(n0 + sg) * HID + k]      = h0;
                h1last[(size_t)(n0 + sg + 8) * HID + k]  = h1;
                h1last[(size_t)(n0 + sg + 16) * HID + k] = h2;
                h1last[(size_t)(n0 + sg + 24) * HID + k] = h3;
            }
        }

        if (t0 + tc < Tt) {
            cS[(size_t)(n0 + sg) * HID + k]      = c0;
            cS[(size_t)(n0 + sg + 8) * HID + k]  = c1;
            cS[(size_t)(n0 + sg + 16) * HID + k] = c2;
            cS[(size_t)(n0 + sg + 24) * HID + k] = c3;
            hS[(size_t)(n0 + sg) * HID + k]      = sH[sg][k];
            hS[(size_t)(n0 + sg + 8) * HID + k]  = sH[sg + 8][k];
            hS[(size_t)(n0 + sg + 16) * HID + k] = sH[sg + 16][k];
            hS[(size_t)(n0 + sg + 24) * HID + k] = sH[sg + 24][k];
        }
        __syncthreads();
    }
}

// ---------------- GAT1 projection: H1 = h @ W1 ; a_src/a_dst per head ----------------
__global__ __launch_bounds__(256) void k_gproj1(
    const float* __restrict__ hl, const float* __restrict__ W1,
    const float* __restrict__ as1, const float* __restrict__ ad1,
    float* __restrict__ H1, float* __restrict__ a_s, float* __restrict__ a_d)
{
    __shared__ float sh[64];
    const int n = blockIdx.x, tid = threadIdx.x;
    if (tid < 64) sh[tid] = hl[(size_t)n * 64 + tid];
    __syncthreads();
    float acc = 0.f;
    #pragma unroll 8
    for (int j = 0; j < 64; ++j) acc += sh[j] * W1[j * 256 + tid];
    H1[(size_t)n * 256 + tid] = acc;
    float ls = acc * as1[tid], ld = acc * ad1[tid];
    #pragma unroll
    for (int off = 32; off >= 1; off >>= 1) { ls += __shfl_down(ls, off); ld += __shfl_down(ld, off); }
    if ((tid & 63) == 0) { a_s[n * 4 + (tid >> 6)] = ls; a_d[n * 4 + (tid >> 6)] = ld; }
}

// ---------------- edge max (4 heads) ----------------
__global__ void k_emax1(const int* __restrict__ ei, const float* __restrict__ a_s,
                        const float* __restrict__ a_d, float* __restrict__ m, int E, int Et)
{
    int idx = blockIdx.x * blockDim.x + threadIdx.x;
    if (idx >= Et * 4) return;
    int e = idx >> 2, h = idx & 3;
    int s, d;
    if (e < E) { s = ei[e]; d = ei[E + e]; } else { s = d = e - E; }
    float a = a_s[s * 4 + h] + a_d[d * 4 + h];
    float l = a > 0.f ? a : NEG * a;
    atomicMaxF(&m[d * 4 + h], l);
}

// ---------------- edge scatter (4 heads x 64) ----------------
__global__ __launch_bounds__(256) void k_escat1(
    const int* __restrict__ ei, const float* __restrict__ a_s, const float* __restrict__ a_d,
    const float* __restrict__ m, float* __restrict__ ssum,
    const float* __restrict__ H1, float* __restrict__ un, int E, int Et)
{
    int e = blockIdx.x;
    int tid = threadIdx.x, h = tid >> 6;
    int s, d;
    if (e < E) { s = ei[e]; d = ei[E + e]; } else { s = d = e - E; }
    float a = a_s[s * 4 + h] + a_d[d * 4 + h];
    float l = a > 0.f ? a : NEG * a;
    float ev = expf(l - m[d * 4 + h]);
    if ((tid & 63) == 0) atomicAdd(&ssum[d * 4 + h], ev);
    atomicAdd(&un[(size_t)d * 256 + tid], ev * H1[(size_t)s * 256 + tid]);
}

// ---------------- GAT1 finalize: /sum + bias + relu (in place -> h2) ----------------
__global__ void k_efin1(float* __restrict__ un, const float* __restrict__ ssum,
                        const float* __restrict__ b1, int N)
{
    int idx = blockIdx.x * blockDim.x + threadIdx.x;
    if (idx >= N * 256) return;
    int n = idx >> 8, k = idx & 255, h = k >> 6;
    float v = un[idx] / ssum[n * 4 + h] + b1[k];
    un[idx] = v > 0.f ? v : 0.f;
}

// ---------------- GAT2 projection ----------------
__global__ __launch_bounds__(256) void k_gproj2(
    const float* __restrict__ h2, const float* __restrict__ W2,
    const float* __restrict__ as2, const float* __restrict__ ad2,
    float* __restrict__ H2, float* __restrict__ a2s, float* __restrict__ a2d)
{
    __shared__ float sh2[4][256];
    const int tid = threadIdx.x;
    const int n0 = blockIdx.x * 4;
    for (int idx = tid; idx < 1024; idx += 256)
        sh2[idx >> 8][idx & 255] = h2[(size_t)(n0 + (idx >> 8)) * 256 + (idx & 255)];
    __syncthreads();
    int w = tid >> 6, L = tid & 63, c = L & 31, half = L >> 5;
    float acc = 0.f;
    #pragma unroll 8
    for (int j = 0; j < 128; ++j) acc += sh2[w][half * 128 + j] * W2[(half * 128 + j) * 32 + c];
    acc += __shfl_down(acc, 32);
    float ls = 0.f, ld = 0.f;
    if (L < 32) {
        H2[(size_t)(n0 + w) * 32 + c] = acc;
        ls = acc * as2[c]; ld = acc * ad2[c];
    }
    #pragma unroll
    for (int off = 16; off >= 1; off >>= 1) { ls += __shfl_down(ls, off); ld += __shfl_down(ld, off); }
    if (L == 0) { a2s[n0 + w] = ls; a2d[n0 + w] = ld; }
}

// ---------------- edge max (1 head) ----------------
__global__ void k_emax2(const int* __restrict__ ei, const float* __restrict__ a_s,
                        const float* __restrict__ a_d, float* __restrict__ m, int E, int Et)
{
    int e = blockIdx.x * blockDim.x + threadIdx.x;
    if (e >= Et) return;
    int s, d;
    if (e < E) { s = ei[e]; d = ei[E + e]; } else { s = d = e - E; }
    float a = a_s[s] + a_d[d];
    float l = a > 0.f ? a : NEG * a;
    atomicMaxF(&m[d], l);
}

// ---------------- edge scatter (32 cols) into d_out ----------------
__global__ __launch_bounds__(256) void k_escat2(
    const int* __restrict__ ei, const float* __restrict__ a_s, const float* __restrict__ a_d,
    const float* __restrict__ m, float* __restrict__ ssum,
    const float* __restrict__ H2, float* __restrict__ outp, int E, int Et)
{
    int idx = blockIdx.x * blockDim.x + threadIdx.x;
    if (idx >= Et * 32) return;
    int e = idx >> 5, c = idx & 31;
    int s, d;
    if (e < E) { s = ei[e]; d = ei[E + e]; } else { s = d = e - E; }
    float a = a_s[s] + a_d[d];
    float l = a > 0.f ? a : NEG * a;
    float ev = expf(l - m[d]);
    if (c == 0) atomicAdd(&ssum[d], ev);
    atomicAdd(&outp[(size_t)d * 32 + c], ev * H2[(size_t)s * 32 + c]);
}

// ---------------- GAT2 finalize ----------------
__global__ void k_efin2(float* __restrict__ outp, const float* __restrict__ ssum,
                        const float* __restrict__ b2, int N)
{
    int idx = blockIdx.x * blockDim.x + threadIdx.x;
    if (idx >= N * 32) return;
    outp[idx] = outp[idx] / ssum[idx >> 5] + b2[idx & 31];
}

__global__ void k_neginf(float* __restrict__ p, int n)
{
    int idx = blockIdx.x * blockDim.x + threadIdx.x;
    if (idx < n) p[idx] = -INFINITY;
}

static inline int cdiv(long long a, long long b) { return (int)((a + b - 1) / b); }

extern "C" void kernel_launch(void* const* d_in, const int* in_sizes, int n_in,
                              void* d_out, int out_size, void* d_ws, size_t ws_size,
                              hipStream_t stream)
{
    const float* x    = (const float*)d_in[0];
    const int*   ei   = (const int*)d_in[1];
    const float* Wih0 = (const float*)d_in[2];
    const float* Whh0 = (const float*)d_in[3];
    const float* bih0 = (const float*)d_in[4];
    const float* bhh0 = (const float*)d_in[5];
    const float* Wih1 = (const float*)d_in[6];
    const float* Whh1 = (const float*)d_in[7];
    const float* bih1 = (const float*)d_in[8];
    const float* bhh1 = (const float*)d_in[9];
    const float* W1   = (const float*)d_in[10];
    const float* as1  = (const float*)d_in[11];
    const float* ad1  = (const float*)d_in[12];
    const float* b1   = (const float*)d_in[13];
    const float* W2   = (const float*)d_in[14];
    const float* as2  = (const float*)d_in[15];
    const float* ad2  = (const float*)d_in[16];
    const float* b2   = (const float*)d_in[17];
    float* outp = (float*)d_out;

    const int N  = in_sizes[0] / (Tt * INP);
    const int E  = in_sizes[1] / 2;
    const int Et = E + N;
    const int NG = N / GRP;                 // 32-seq groups

    float* ws = (float*)d_ws;
    const size_t N64 = (size_t)N * 64;

    float* h1last = ws;               // N*64, persists LSTM -> GAT
    float* rA = ws + N64;

    // region A (LSTM)
    float* h0s = rA;
    float* c0s = rA + N64;
    float* h1s = rA + 2 * N64;
    float* c1s = rA + 3 * N64;
    float* h0chunk = rA + 4 * N64;    // N*C*64

    long long availChunkRows = (long long)(ws_size / 4) - (long long)(5 * N64);
    int C = (int)(availChunkRows / (long long)N64);
    if (C > Tt) C = Tt;
    if (C < 1) C = 1;

    // region B (GAT) — overlays region A
    float* H1   = rA;                         // N*256
    float* un1  = H1 + (size_t)N * 256;       // N*256 (becomes h2)
    float* H2   = un1 + (size_t)N * 256;      // N*32
    float* as1p = H2 + (size_t)N * 32;        // N*4
    float* ad1p = as1p + (size_t)N * 4;
    float* m1   = ad1p + (size_t)N * 4;
    float* s1   = m1 + (size_t)N * 4;
    float* a2s  = s1 + (size_t)N * 4;         // N
    float* a2d  = a2s + N;
    float* m2   = a2d + N;
    float* s2   = m2 + N;

    // ---- LSTM (chunked over T; 256 blocks, 1/CU by LDS) ----
    for (int t0 = 0; t0 < Tt; t0 += C) {
        int tc = Tt - t0 < C ? Tt - t0 : C;
        k_lstm0<<<dim3(256), dim3(512), 0, stream>>>(x, Wih0, Whh0, bih0, bhh0,
                                                     h0chunk, h0s, c0s, t0, tc, C, NG);
        k_lstm1<<<dim3(256), dim3(512), 0, stream>>>(h0chunk, Wih1, Whh1, bih1, bhh1,
                                                     h1last, h1s, c1s, t0, tc, C, NG);
    }

    // ---- init GAT accumulators ----
    hipMemsetAsync(un1, 0, (size_t)N * 256 * 4, stream);
    hipMemsetAsync(s1, 0, (size_t)N * 4 * 4, stream);
    hipMemsetAsync(s2, 0, (size_t)N * 4, stream);
    hipMemsetAsync(outp, 0, (size_t)N * 32 * 4, stream);
    k_neginf<<<cdiv((long long)N * 4, 256), 256, 0, stream>>>(m1, N * 4);
    k_neginf<<<cdiv(N, 256), 256, 0, stream>>>(m2, N);

    // ---- GAT layer 1 ----
    k_gproj1<<<dim3(N), dim3(256), 0, stream>>>(h1last, W1, as1, ad1, H1, as1p, ad1p);
    k_emax1<<<cdiv((long long)Et * 4, 256), 256, 0, stream>>>(ei, as1p, ad1p, m1, E, Et);
    k_escat1<<<dim3(Et), dim3(256), 0, stream>>>(ei, as1p, ad1p, m1, s1, H1, un1, E, Et);
    k_efin1<<<cdiv((long long)N * 256, 256), 256, 0, stream>>>(un1, s1, b1, N);

    // ---- GAT layer 2 ----
    k_gproj2<<<dim3(N / 4), dim3(256), 0, stream>>>(un1, W2, as2, ad2, H2, a2s, a2d);
    k_emax2<<<cdiv(Et, 256), 256, 0, stream>>>(ei, a2s, a2d, m2, E, Et);
    k_escat2<<<cdiv((long long)Et * 32, 256), 256, 0, stream>>>(ei, a2s, a2d, m2, s2, H2, outp, E, Et);
    k_efin2<<<cdiv((long long)N * 32, 256), 256, 0, stream>>>(outp, s2, b2, N);
}

// Round 4
// 1356.388 us; speedup vs baseline: 67.9563x; 1.4951x over previous
//
#include <hip/hip_runtime.h>
#include <math.h>

#define Tt  30
#define INP 32
#define HID 64
#define G4  256
#define GRP 32      // sequences per group/block
#define NEG 0.2f

typedef __attribute__((ext_vector_type(8))) _Float16 half8;
typedef __attribute__((ext_vector_type(4))) float    f4;

#define MFMA16(a,b,c) __builtin_amdgcn_mfma_f32_16x16x32_f16((a),(b),(c),0,0,0)

__device__ __forceinline__ float sigm(float v) { return 1.f / (1.f + expf(-v)); }

__device__ __forceinline__ unsigned short h2b(_Float16 h){ union{_Float16 f; unsigned short u;} c; c.f=h; return c.u; }
__device__ __forceinline__ _Float16 b2h(unsigned short u){ union{_Float16 f; unsigned short u;} c; c.u=u; return c.f; }

__device__ __forceinline__ void atomicMaxF(float* addr, float v) {
    if (v >= 0.f) atomicMax((int*)addr, __float_as_int(v));
    else          atomicMin((unsigned int*)addr, __float_as_uint(v));
}

// one K-tile step: A m-tiles {fidA0,fidA1}, B k-tile ktB, 4 C tiles, 3-MFMA split (drop lo*lo)
#define KSTEP(pAh, pAl, fidA0, fidA1, ktB) {                                      \
    const half8 a0h = *(const half8*)((pAh) + (fidA0)*512 + ln8);                 \
    const half8 a0l = *(const half8*)((pAl) + (fidA0)*512 + ln8);                 \
    const half8 a1h = *(const half8*)((pAh) + (fidA1)*512 + ln8);                 \
    const half8 a1l = *(const half8*)((pAl) + (fidA1)*512 + ln8);                 \
    const half8 b0h = *(const half8*)(sBh + ((ktB)*16 + nt0)*512 + ln8);          \
    const half8 b0l = *(const half8*)(sBl + ((ktB)*16 + nt0)*512 + ln8);          \
    const half8 b1h = *(const half8*)(sBh + ((ktB)*16 + nt1)*512 + ln8);          \
    const half8 b1l = *(const half8*)(sBl + ((ktB)*16 + nt1)*512 + ln8);          \
    accA0 = MFMA16(a0h,b0h,accA0); accA0 = MFMA16(a0l,b0h,accA0); accA0 = MFMA16(a0h,b0l,accA0); \
    accA1 = MFMA16(a0h,b1h,accA1); accA1 = MFMA16(a0l,b1h,accA1); accA1 = MFMA16(a0h,b1l,accA1); \
    accB0 = MFMA16(a1h,b0h,accB0); accB0 = MFMA16(a1l,b0h,accB0); accB0 = MFMA16(a1h,b0l,accB0); \
    accB1 = MFMA16(a1h,b1h,accB1); accB1 = MFMA16(a1l,b1h,accB1); accB1 = MFMA16(a1h,b1l,accB1); \
}

// write one C tile (16x16) into gate buffer sG (pitch 260 floats), rows local to m-tile
#define WRC(acc, nt) {                                                            \
    int _b = quad*4*260 + (nt)*16 + ln;                                           \
    sG[_b] = (acc).x; sG[_b+260] = (acc).y; sG[_b+520] = (acc).z; sG[_b+780] = (acc).w; \
}

// ================= LSTM layer 0 (MFMA f16 hi/lo split) =================
// block 512 thr = 8 waves. 32 seqs/group. A = [x_t(K=32) | h(K=64)] (M=32,K=96), B = [Wih0;Whh0] (96x256).
// wave w: n-tiles {2w,2w+1}, both m-tiles. Epilogue: 2 phases of 16 seqs via LDS gate buffer.
__global__ __launch_bounds__(512) void k_lstm0(
    const float* __restrict__ x, const float* __restrict__ Wih, const float* __restrict__ Whh,
    const float* __restrict__ bih, const float* __restrict__ bhh,
    unsigned int* __restrict__ hseq, float* __restrict__ hS, float* __restrict__ cS,
    int t0, int tc, int C, int NG)
{
    __shared__ __align__(16) char RAW[123136];
    _Float16* sBh  = (_Float16*)RAW;                 // 3kt*16nt*512 = 24576 h = 49152 B
    _Float16* sBl  = (_Float16*)(RAW + 49152);
    _Float16* sAhh = (_Float16*)(RAW + 98304);       // h-frags hi: 4 ids * 512 = 4096 B
    _Float16* sAhl = (_Float16*)(RAW + 102400);
    _Float16* sAxh = (_Float16*)(RAW + 106496);      // x-frags hi: 2 ids * 512 = 2048 B
    _Float16* sAxl = (_Float16*)(RAW + 108544);
    float*    sG   = (float*)(RAW + 106496);         // 16x260 fp32 = 16640 B (aliases sAx; x dead by then)

    const int tid  = threadIdx.x;
    const int lane = tid & 63, wv = tid >> 6;
    const int quad = lane >> 4, ln = lane & 15, ln8 = lane * 8;
    const int nt0 = wv * 2, nt1 = wv * 2 + 1;
    const int k = tid & 63, sg = tid >> 6;           // gate-phase mapping

    // stage weights into frag order, hi/lo split
    for (int idx = tid; idx < 96 * 256; idx += 512) {
        int r = idx >> 8, n = idx & 255;
        float v = (r < 32) ? Wih[r * 256 + n] : Whh[(r - 32) * 256 + n];
        _Float16 hi = (_Float16)v; _Float16 lo = (_Float16)(v - (float)hi);
        int off = ((r >> 5) * 16 + (n >> 4)) * 512 + ((r & 31) >> 3) * 128 + (n & 15) * 8 + (r & 7);
        sBh[off] = hi; sBl[off] = lo;
    }
    const float bb0 = bih[nt0 * 16 + ln] + bhh[nt0 * 16 + ln];
    const float bb1 = bih[nt1 * 16 + ln] + bhh[nt1 * 16 + ln];
    const bool save = (t0 + tc < Tt);

    for (int g = blockIdx.x; g < NG; g += gridDim.x) {
        const int n0 = g * GRP;
        float c0, c1, c2, c3;
        if (t0 == 0) {
            c0 = c1 = c2 = c3 = 0.f;
            #pragma unroll
            for (int p4 = 0; p4 < 4; ++p4) { int idx = tid + p4 * 512; sAhh[idx] = (_Float16)0.f; sAhl[idx] = (_Float16)0.f; }
        } else {
            c0 = cS[(size_t)(n0 + sg) * HID + k];
            c1 = cS[(size_t)(n0 + sg + 8) * HID + k];
            c2 = cS[(size_t)(n0 + sg + 16) * HID + k];
            c3 = cS[(size_t)(n0 + sg + 24) * HID + k];
            #pragma unroll
            for (int p4 = 0; p4 < 4; ++p4) {
                int idx = tid + p4 * 512;
                int m = idx >> 6, kk = idx & 63;
                float v = hS[(size_t)(n0 + m) * HID + kk];
                _Float16 hi = (_Float16)v; _Float16 lo = (_Float16)(v - (float)hi);
                int off = ((kk >> 5) * 2 + (m >> 4)) * 512 + ((kk & 31) >> 3) * 128 + (m & 15) * 8 + (kk & 7);
                sAhh[off] = hi; sAhl[off] = lo;
            }
        }

        for (int tt = 0; tt < tc; ++tt) {
            const int t = t0 + tt;
            // stage x_t frags (K-pos 0..31, kt=0, fid = m-tile)
            #pragma unroll
            for (int p2 = 0; p2 < 2; ++p2) {
                int idx = tid + p2 * 512;
                int s = idx >> 5, j = idx & 31;
                float v = x[(size_t)(n0 + s) * Tt * INP + t * INP + j];
                _Float16 hi = (_Float16)v; _Float16 lo = (_Float16)(v - (float)hi);
                int off = (s >> 4) * 512 + (j >> 3) * 128 + (s & 15) * 8 + (j & 7);
                sAxh[off] = hi; sAxl[off] = lo;
            }
            __syncthreads();                                   // B1: x+h frags visible

            f4 accA0 = {bb0, bb0, bb0, bb0}, accA1 = {bb1, bb1, bb1, bb1};
            f4 accB0 = {bb0, bb0, bb0, bb0}, accB1 = {bb1, bb1, bb1, bb1};
            KSTEP(sAxh, sAxl, 0, 1, 0);
            KSTEP(sAhh, sAhl, 0, 1, 1);
            KSTEP(sAhh, sAhl, 2, 3, 2);
            __syncthreads();                                   // B2: A reads done, sG writable

            WRC(accA0, nt0); WRC(accA1, nt1);
            __syncthreads();                                   // B3
            {   // gate phase 0: seqs 0..15
                int b0 = sg * 260 + k;
                float i0 = sigm(sG[b0]), f0 = sigm(sG[b0+64]), g0 = tanhf(sG[b0+128]), o0 = sigm(sG[b0+192]);
                c0 = f0 * c0 + i0 * g0; float hv0 = o0 * tanhf(c0);
                int b1 = (sg + 8) * 260 + k;
                float i1 = sigm(sG[b1]), f1 = sigm(sG[b1+64]), g1 = tanhf(sG[b1+128]), o1 = sigm(sG[b1+192]);
                c1 = f1 * c1 + i1 * g1; float hv1 = o1 * tanhf(c1);
                _Float16 ah = (_Float16)hv0; _Float16 al = (_Float16)(hv0 - (float)ah);
                _Float16 bh = (_Float16)hv1; _Float16 bl = (_Float16)(hv1 - (float)bh);
                int hid = (k >> 5) * 2 + 0;
                int koff = ((k & 31) >> 3) * 128 + (k & 7);
                int oA = hid * 512 + koff + sg * 8, oB = hid * 512 + koff + (sg + 8) * 8;
                sAhh[oA] = ah; sAhl[oA] = al; sAhh[oB] = bh; sAhl[oB] = bl;
                hseq[((size_t)(n0 + sg) * C + tt) * 64 + k]     = ((unsigned)h2b(ah) << 16) | h2b(al);
                hseq[((size_t)(n0 + sg + 8) * C + tt) * 64 + k] = ((unsigned)h2b(bh) << 16) | h2b(bl);
                if (save && tt == tc - 1) {
                    hS[(size_t)(n0 + sg) * HID + k] = hv0;     cS[(size_t)(n0 + sg) * HID + k] = c0;
                    hS[(size_t)(n0 + sg + 8) * HID + k] = hv1; cS[(size_t)(n0 + sg + 8) * HID + k] = c1;
                }
            }
            __syncthreads();                                   // B4
            WRC(accB0, nt0); WRC(accB1, nt1);
            __syncthreads();                                   // B5
            {   // gate phase 1: seqs 16..31
                int b0 = sg * 260 + k;
                float i0 = sigm(sG[b0]), f0 = sigm(sG[b0+64]), g0 = tanhf(sG[b0+128]), o0 = sigm(sG[b0+192]);
                c2 = f0 * c2 + i0 * g0; float hv0 = o0 * tanhf(c2);
                int b1 = (sg + 8) * 260 + k;
                float i1 = sigm(sG[b1]), f1 = sigm(sG[b1+64]), g1 = tanhf(sG[b1+128]), o1 = sigm(sG[b1+192]);
                c3 = f1 * c3 + i1 * g1; float hv1 = o1 * tanhf(c3);
                _Float16 ah = (_Float16)hv0; _Float16 al = (_Float16)(hv0 - (float)ah);
                _Float16 bh = (_Float16)hv1; _Float16 bl = (_Float16)(hv1 - (float)bh);
                int hid = (k >> 5) * 2 + 1;
                int koff = ((k & 31) >> 3) * 128 + (k & 7);
                int oA = hid * 512 + koff + sg * 8, oB = hid * 512 + koff + (sg + 8) * 8;
                sAhh[oA] = ah; sAhl[oA] = al; sAhh[oB] = bh; sAhl[oB] = bl;
                hseq[((size_t)(n0 + sg + 16) * C + tt) * 64 + k] = ((unsigned)h2b(ah) << 16) | h2b(al);
                hseq[((size_t)(n0 + sg + 24) * C + tt) * 64 + k] = ((unsigned)h2b(bh) << 16) | h2b(bl);
                if (save && tt == tc - 1) {
                    hS[(size_t)(n0 + sg + 16) * HID + k] = hv0; cS[(size_t)(n0 + sg + 16) * HID + k] = c2;
                    hS[(size_t)(n0 + sg + 24) * HID + k] = hv1; cS[(size_t)(n0 + sg + 24) * HID + k] = c3;
                }
            }
            __syncthreads();                                   // B6: sG/sAx reusable next t
        }
    }
}

// ================= LSTM layer 1 (MFMA f16 hi/lo split) =================
// A = [h0_t(K=64) | h1(K=64)] (M=32,K=128), B = [Wih1;Whh1] (128x256). Input h0 packed (hi,lo) in uint.
__global__ __launch_bounds__(512) void k_lstm1(
    const unsigned int* __restrict__ hseq, const float* __restrict__ Wih, const float* __restrict__ Whh,
    const float* __restrict__ bih, const float* __restrict__ bhh,
    float* __restrict__ h1last, float* __restrict__ hS, float* __restrict__ cS,
    int t0, int tc, int C, int NG)
{
    __shared__ __align__(16) char RAW[155904];
    _Float16* sBh  = (_Float16*)RAW;                 // 4kt*16nt*512 = 32768 h = 65536 B
    _Float16* sBl  = (_Float16*)(RAW + 65536);
    _Float16* sAhh = (_Float16*)(RAW + 131072);      // h-frags: 4 ids * 512 = 4096 B
    _Float16* sAhl = (_Float16*)(RAW + 135168);
    _Float16* sAxh = (_Float16*)(RAW + 139264);      // x-frags: 4 ids * 512 = 4096 B
    _Float16* sAxl = (_Float16*)(RAW + 143360);
    float*    sG   = (float*)(RAW + 139264);         // 16x260 fp32 (aliases sAx)

    const int tid  = threadIdx.x;
    const int lane = tid & 63, wv = tid >> 6;
    const int quad = lane >> 4, ln = lane & 15, ln8 = lane * 8;
    const int nt0 = wv * 2, nt1 = wv * 2 + 1;
    const int k = tid & 63, sg = tid >> 6;

    for (int idx = tid; idx < 128 * 256; idx += 512) {
        int r = idx >> 8, n = idx & 255;
        float v = (r < 64) ? Wih[r * 256 + n] : Whh[(r - 64) * 256 + n];
        _Float16 hi = (_Float16)v; _Float16 lo = (_Float16)(v - (float)hi);
        int off = ((r >> 5) * 16 + (n >> 4)) * 512 + ((r & 31) >> 3) * 128 + (n & 15) * 8 + (r & 7);
        sBh[off] = hi; sBl[off] = lo;
    }
    const float bb0 = bih[nt0 * 16 + ln] + bhh[nt0 * 16 + ln];
    const float bb1 = bih[nt1 * 16 + ln] + bhh[nt1 * 16 + ln];
    const bool save = (t0 + tc < Tt);

    for (int g = blockIdx.x; g < NG; g += gridDim.x) {
        const int n0 = g * GRP;
        float c0, c1, c2, c3;
        if (t0 == 0) {
            c0 = c1 = c2 = c3 = 0.f;
            #pragma unroll
            for (int p4 = 0; p4 < 4; ++p4) { int idx = tid + p4 * 512; sAhh[idx] = (_Float16)0.f; sAhl[idx] = (_Float16)0.f; }
        } else {
            c0 = cS[(size_t)(n0 + sg) * HID + k];
            c1 = cS[(size_t)(n0 + sg + 8) * HID + k];
            c2 = cS[(size_t)(n0 + sg + 16) * HID + k];
            c3 = cS[(size_t)(n0 + sg + 24) * HID + k];
            #pragma unroll
            for (int p4 = 0; p4 < 4; ++p4) {
                int idx = tid + p4 * 512;
                int m = idx >> 6, kk = idx & 63;
                float v = hS[(size_t)(n0 + m) * HID + kk];
                _Float16 hi = (_Float16)v; _Float16 lo = (_Float16)(v - (float)hi);
                int off = ((kk >> 5) * 2 + (m >> 4)) * 512 + ((kk & 31) >> 3) * 128 + (m & 15) * 8 + (kk & 7);
                sAhh[off] = hi; sAhl[off] = lo;
            }
        }

        for (int tt = 0; tt < tc; ++tt) {
            const int t = t0 + tt;
            // stage x frags from packed h0 (K-pos j 0..63 -> kt = j>>5)
            #pragma unroll
            for (int p4 = 0; p4 < 4; ++p4) {
                int idx = tid + p4 * 512;
                int s = idx >> 6, j = idx & 63;
                unsigned v = hseq[((size_t)(n0 + s) * C + tt) * 64 + j];
                int off = ((j >> 5) * 2 + (s >> 4)) * 512 + ((j & 31) >> 3) * 128 + (s & 15) * 8 + (j & 7);
                sAxh[off] = b2h((unsigned short)(v >> 16));
                sAxl[off] = b2h((unsigned short)(v & 0xffff));
            }
            __syncthreads();                                   // B1

            f4 accA0 = {bb0, bb0, bb0, bb0}, accA1 = {bb1, bb1, bb1, bb1};
            f4 accB0 = {bb0, bb0, bb0, bb0}, accB1 = {bb1, bb1, bb1, bb1};
            KSTEP(sAxh, sAxl, 0, 1, 0);
            KSTEP(sAxh, sAxl, 2, 3, 1);
            KSTEP(sAhh, sAhl, 0, 1, 2);
            KSTEP(sAhh, sAhl, 2, 3, 3);
            __syncthreads();                                   // B2

            WRC(accA0, nt0); WRC(accA1, nt1);
            __syncthreads();                                   // B3
            {   // gate phase 0: seqs 0..15
                int b0 = sg * 260 + k;
                float i0 = sigm(sG[b0]), f0 = sigm(sG[b0+64]), g0 = tanhf(sG[b0+128]), o0 = sigm(sG[b0+192]);
                c0 = f0 * c0 + i0 * g0; float hv0 = o0 * tanhf(c0);
                int b1 = (sg + 8) * 260 + k;
                float i1 = sigm(sG[b1]), f1 = sigm(sG[b1+64]), g1 = tanhf(sG[b1+128]), o1 = sigm(sG[b1+192]);
                c1 = f1 * c1 + i1 * g1; float hv1 = o1 * tanhf(c1);
                _Float16 ah = (_Float16)hv0; _Float16 al = (_Float16)(hv0 - (float)ah);
                _Float16 bh = (_Float16)hv1; _Float16 bl = (_Float16)(hv1 - (float)bh);
                int hid = (k >> 5) * 2 + 0;
                int koff = ((k & 31) >> 3) * 128 + (k & 7);
                int oA = hid * 512 + koff + sg * 8, oB = hid * 512 + koff + (sg + 8) * 8;
                sAhh[oA] = ah; sAhl[oA] = al; sAhh[oB] = bh; sAhl[oB] = bl;
                if (t == Tt - 1) {
                    h1last[(size_t)(n0 + sg) * HID + k] = hv0;
                    h1last[(size_t)(n0 + sg + 8) * HID + k] = hv1;
                }
                if (save && tt == tc - 1) {
                    hS[(size_t)(n0 + sg) * HID + k] = hv0;     cS[(size_t)(n0 + sg) * HID + k] = c0;
                    hS[(size_t)(n0 + sg + 8) * HID + k] = hv1; cS[(size_t)(n0 + sg + 8) * HID + k] = c1;
                }
            }
            __syncthreads();                                   // B4
            WRC(accB0, nt0); WRC(accB1, nt1);
            __syncthreads();                                   // B5
            {   // gate phase 1: seqs 16..31
                int b0 = sg * 260 + k;
                float i0 = sigm(sG[b0]), f0 = sigm(sG[b0+64]), g0 = tanhf(sG[b0+128]), o0 = sigm(sG[b0+192]);
                c2 = f0 * c2 + i0 * g0; float hv0 = o0 * tanhf(c2);
                int b1 = (sg + 8) * 260 + k;
                float i1 = sigm(sG[b1]), f1 = sigm(sG[b1+64]), g1 = tanhf(sG[b1+128]), o1 = sigm(sG[b1+192]);
                c3 = f1 * c3 + i1 * g1; float hv1 = o1 * tanhf(c3);
                _Float16 ah = (_Float16)hv0; _Float16 al = (_Float16)(hv0 - (float)ah);
                _Float16 bh = (_Float16)hv1; _Float16 bl = (_Float16)(hv1 - (float)bh);
                int hid = (k >> 5) * 2 + 1;
                int koff = ((k & 31) >> 3) * 128 + (k & 7);
                int oA = hid * 512 + koff + sg * 8, oB = hid * 512 + koff + (sg + 8) * 8;
                sAhh[oA] = ah; sAhl[oA] = al; sAhh[oB] = bh; sAhl[oB] = bl;
                if (t == Tt - 1) {
                    h1last[(size_t)(n0 + sg + 16) * HID + k] = hv0;
                    h1last[(size_t)(n0 + sg + 24) * HID + k] = hv1;
                }
                if (save && tt == tc - 1) {
                    hS[(size_t)(n0 + sg + 16) * HID + k] = hv0; cS[(size_t)(n0 + sg + 16) * HID + k] = c2;
                    hS[(size_t)(n0 + sg + 24) * HID + k] = hv1; cS[(size_t)(n0 + sg + 24) * HID + k] = c3;
                }
            }
            __syncthreads();                                   // B6
        }
    }
}

// ---------------- GAT1 projection ----------------
__global__ __launch_bounds__(256) void k_gproj1(
    const float* __restrict__ hl, const float* __restrict__ W1,
    const float* __restrict__ as1, const float* __restrict__ ad1,
    float* __restrict__ H1, float* __restrict__ a_s, float* __restrict__ a_d)
{
    __shared__ float sh[64];
    const int n = blockIdx.x, tid = threadIdx.x;
    if (tid < 64) sh[tid] = hl[(size_t)n * 64 + tid];
    __syncthreads();
    float acc = 0.f;
    #pragma unroll 8
    for (int j = 0; j < 64; ++j) acc += sh[j] * W1[j * 256 + tid];
    H1[(size_t)n * 256 + tid] = acc;
    float ls = acc * as1[tid], ld = acc * ad1[tid];
    #pragma unroll
    for (int off = 32; off >= 1; off >>= 1) { ls += __shfl_down(ls, off); ld += __shfl_down(ld, off); }
    if ((tid & 63) == 0) { a_s[n * 4 + (tid >> 6)] = ls; a_d[n * 4 + (tid >> 6)] = ld; }
}

// ---------------- edge max (4 heads) ----------------
__global__ void k_emax1(const int* __restrict__ ei, const float* __restrict__ a_s,
                        const float* __restrict__ a_d, float* __restrict__ m, int E, int Et)
{
    int idx = blockIdx.x * blockDim.x + threadIdx.x;
    if (idx >= Et * 4) return;
    int e = idx >> 2, h = idx & 3;
    int s, d;
    if (e < E) { s = ei[e]; d = ei[E + e]; } else { s = d = e - E; }
    float a = a_s[s * 4 + h] + a_d[d * 4 + h];
    float l = a > 0.f ? a : NEG * a;
    atomicMaxF(&m[d * 4 + h], l);
}

// ---------------- edge scatter (4 heads x 64) ----------------
__global__ __launch_bounds__(256) void k_escat1(
    const int* __restrict__ ei, const float* __restrict__ a_s, const float* __restrict__ a_d,
    const float* __restrict__ m, float* __restrict__ ssum,
    const float* __restrict__ H1, float* __restrict__ un, int E, int Et)
{
    int e = blockIdx.x;
    int tid = threadIdx.x, h = tid >> 6;
    int s, d;
    if (e < E) { s = ei[e]; d = ei[E + e]; } else { s = d = e - E; }
    float a = a_s[s * 4 + h] + a_d[d * 4 + h];
    float l = a > 0.f ? a : NEG * a;
    float ev = expf(l - m[d * 4 + h]);
    if ((tid & 63) == 0) atomicAdd(&ssum[d * 4 + h], ev);
    atomicAdd(&un[(size_t)d * 256 + tid], ev * H1[(size_t)s * 256 + tid]);
}

// ---------------- GAT1 finalize ----------------
__global__ void k_efin1(float* __restrict__ un, const float* __restrict__ ssum,
                        const float* __restrict__ b1, int N)
{
    int idx = blockIdx.x * blockDim.x + threadIdx.x;
    if (idx >= N * 256) return;
    int n = idx >> 8, kk = idx & 255, h = kk >> 6;
    float v = un[idx] / ssum[n * 4 + h] + b1[kk];
    un[idx] = v > 0.f ? v : 0.f;
}

// ---------------- GAT2 projection ----------------
__global__ __launch_bounds__(256) void k_gproj2(
    const float* __restrict__ h2, const float* __restrict__ W2,
    const float* __restrict__ as2, const float* __restrict__ ad2,
    float* __restrict__ H2, float* __restrict__ a2s, float* __restrict__ a2d)
{
    __shared__ float sh2[4][256];
    const int tid = threadIdx.x;
    const int n0 = blockIdx.x * 4;
    for (int idx = tid; idx < 1024; idx += 256)
        sh2[idx >> 8][idx & 255] = h2[(size_t)(n0 + (idx >> 8)) * 256 + (idx & 255)];
    __syncthreads();
    int w = tid >> 6, L = tid & 63, c = L & 31, half = L >> 5;
    float acc = 0.f;
    #pragma unroll 8
    for (int j = 0; j < 128; ++j) acc += sh2[w][half * 128 + j] * W2[(half * 128 + j) * 32 + c];
    acc += __shfl_down(acc, 32);
    float ls = 0.f, ld = 0.f;
    if (L < 32) {
        H2[(size_t)(n0 + w) * 32 + c] = acc;
        ls = acc * as2[c]; ld = acc * ad2[c];
    }
    #pragma unroll
    for (int off = 16; off >= 1; off >>= 1) { ls += __shfl_down(ls, off); ld += __shfl_down(ld, off); }
    if (L == 0) { a2s[n0 + w] = ls; a2d[n0 + w] = ld; }
}

// ---------------- edge max (1 head) ----------------
__global__ void k_emax2(const int* __restrict__ ei, const float* __restrict__ a_s,
                        const float* __restrict__ a_d, float* __restrict__ m, int E, int Et)
{
    int e = blockIdx.x * blockDim.x + threadIdx.x;
    if (e >= Et) return;
    int s, d;
    if (e < E) { s = ei[e]; d = ei[E + e]; } else { s = d = e - E; }
    float a = a_s[s] + a_d[d];
    float l = a > 0.f ? a : NEG * a;
    atomicMaxF(&m[d], l);
}

// ---------------- edge scatter (32 cols) ----------------
__global__ __launch_bounds__(256) void k_escat2(
    const int* __restrict__ ei, const float* __restrict__ a_s, const float* __restrict__ a_d,
    const float* __restrict__ m, float* __restrict__ ssum,
    const float* __restrict__ H2, float* __restrict__ outp, int E, int Et)
{
    int idx = blockIdx.x * blockDim.x + threadIdx.x;
    if (idx >= Et * 32) return;
    int e = idx >> 5, c = idx & 31;
    int s, d;
    if (e < E) { s = ei[e]; d = ei[E + e]; } else { s = d = e - E; }
    float a = a_s[s] + a_d[d];
    float l = a > 0.f ? a : NEG * a;
    float ev = expf(l - m[d]);
    if (c == 0) atomicAdd(&ssum[d], ev);
    atomicAdd(&outp[(size_t)d * 32 + c], ev * H2[(size_t)s * 32 + c]);
}

// ---------------- GAT2 finalize ----------------
__global__ void k_efin2(float* __restrict__ outp, const float* __restrict__ ssum,
                        const float* __restrict__ b2, int N)
{
    int idx = blockIdx.x * blockDim.x + threadIdx.x;
    if (idx >= N * 32) return;
    outp[idx] = outp[idx] / ssum[idx >> 5] + b2[idx & 31];
}

__global__ void k_neginf(float* __restrict__ p, int n)
{
    int idx = blockIdx.x * blockDim.x + threadIdx.x;
    if (idx < n) p[idx] = -INFINITY;
}

static inline int cdiv(long long a, long long b) { return (int)((a + b - 1) / b); }

extern "C" void kernel_launch(void* const* d_in, const int* in_sizes, int n_in,
                              void* d_out, int out_size, void* d_ws, size_t ws_size,
                              hipStream_t stream)
{
    const float* x    = (const float*)d_in[0];
    const int*   ei   = (const int*)d_in[1];
    const float* Wih0 = (const float*)d_in[2];
    const float* Whh0 = (const float*)d_in[3];
    const float* bih0 = (const float*)d_in[4];
    const float* bhh0 = (const float*)d_in[5];
    const float* Wih1 = (const float*)d_in[6];
    const float* Whh1 = (const float*)d_in[7];
    const float* bih1 = (const float*)d_in[8];
    const float* bhh1 = (const float*)d_in[9];
    const float* W1   = (const float*)d_in[10];
    const float* as1  = (const float*)d_in[11];
    const float* ad1  = (const float*)d_in[12];
    const float* b1   = (const float*)d_in[13];
    const float* W2   = (const float*)d_in[14];
    const float* as2  = (const float*)d_in[15];
    const float* ad2  = (const float*)d_in[16];
    const float* b2   = (const float*)d_in[17];
    float* outp = (float*)d_out;

    const int N  = in_sizes[0] / (Tt * INP);
    const int E  = in_sizes[1] / 2;
    const int Et = E + N;
    const int NG = N / GRP;

    float* ws = (float*)d_ws;
    const size_t N64 = (size_t)N * 64;

    float* h1last = ws;               // N*64, persists LSTM -> GAT
    float* rA = ws + N64;

    // region A (LSTM)
    float* h0s = rA;
    float* c0s = rA + N64;
    float* h1s = rA + 2 * N64;
    float* c1s = rA + 3 * N64;
    unsigned int* h0chunk = (unsigned int*)(rA + 4 * N64);    // N*C*64 packed (hi,lo) f16

    long long availChunkRows = (long long)(ws_size / 4) - (long long)(5 * N64);
    int C = (int)(availChunkRows / (long long)N64);
    if (C > Tt) C = Tt;
    if (C < 1) C = 1;

    // region B (GAT) — overlays region A
    float* H1   = rA;                         // N*256
    float* un1  = H1 + (size_t)N * 256;       // N*256 (becomes h2)
    float* H2   = un1 + (size_t)N * 256;      // N*32
    float* as1p = H2 + (size_t)N * 32;        // N*4
    float* ad1p = as1p + (size_t)N * 4;
    float* m1   = ad1p + (size_t)N * 4;
    float* s1   = m1 + (size_t)N * 4;
    float* a2s  = s1 + (size_t)N * 4;         // N
    float* a2d  = a2s + N;
    float* m2   = a2d + N;
    float* s2   = m2 + N;

    // ---- LSTM (chunked over T; 256 blocks, 1/CU by LDS) ----
    for (int t0 = 0; t0 < Tt; t0 += C) {
        int tc = Tt - t0 < C ? Tt - t0 : C;
        k_lstm0<<<dim3(256), dim3(512), 0, stream>>>(x, Wih0, Whh0, bih0, bhh0,
                                                     h0chunk, h0s, c0s, t0, tc, C, NG);
        k_lstm1<<<dim3(256), dim3(512), 0, stream>>>(h0chunk, Wih1, Whh1, bih1, bhh1,
                                                     h1last, h1s, c1s, t0, tc, C, NG);
    }

    // ---- init GAT accumulators ----
    hipMemsetAsync(un1, 0, (size_t)N * 256 * 4, stream);
    hipMemsetAsync(s1, 0, (size_t)N * 4 * 4, stream);
    hipMemsetAsync(s2, 0, (size_t)N * 4, stream);
    hipMemsetAsync(outp, 0, (size_t)N * 32 * 4, stream);
    k_neginf<<<cdiv((long long)N * 4, 256), 256, 0, stream>>>(m1, N * 4);
    k_neginf<<<cdiv(N, 256), 256, 0, stream>>>(m2, N);

    // ---- GAT layer 1 ----
    k_gproj1<<<dim3(N), dim3(256), 0, stream>>>(h1last, W1, as1, ad1, H1, as1p, ad1p);
    k_emax1<<<cdiv((long long)Et * 4, 256), 256, 0, stream>>>(ei, as1p, ad1p, m1, E, Et);
    k_escat1<<<dim3(Et), dim3(256), 0, stream>>>(ei, as1p, ad1p, m1, s1, H1, un1, E, Et);
    k_efin1<<<cdiv((long long)N * 256, 256), 256, 0, stream>>>(un1, s1, b1, N);

    // ---- GAT layer 2 ----
    k_gproj2<<<dim3(N / 4), dim3(256), 0, stream>>>(un1, W2, as2, ad2, H2, a2s, a2d);
    k_emax2<<<cdiv(Et, 256), 256, 0, stream>>>(ei, a2s, a2d, m2, E, Et);
    k_escat2<<<cdiv((long long)Et * 32, 256), 256, 0, stream>>>(ei, a2s, a2d, m2, s2, H2, outp, E, Et);
    k_efin2<<<cdiv((long long)N * 32, 256), 256, 0, stream>>>(outp, s2, b2, N);
}

// Round 5
// 1314.974 us; speedup vs baseline: 70.0965x; 1.0315x over previous
//
#include <hip/hip_runtime.h>
#include <math.h>

#define Tt  30
#define INP 32
#define HID 64
#define NEG 0.2f
#define SHP 68      // sHlin pitch (floats): +4 pad -> bank-conflict-free frag rebuild
#define SGP 260     // sG pitch (floats)

typedef __attribute__((ext_vector_type(8))) _Float16 half8;
typedef __attribute__((ext_vector_type(4))) float    f4;

#define MFMA16(a,b,c) __builtin_amdgcn_mfma_f32_16x16x32_f16((a),(b),(c),0,0,0)

__device__ __forceinline__ float fsigm(float v){ return __builtin_amdgcn_rcpf(1.f + __expf(-v)); }
__device__ __forceinline__ float ftanh(float v){ return 2.f * __builtin_amdgcn_rcpf(1.f + __expf(-2.f*v)) - 1.f; }

__device__ __forceinline__ unsigned short h2b(_Float16 h){ union{_Float16 f; unsigned short u;} c; c.f=h; return c.u; }
__device__ __forceinline__ _Float16 b2h(unsigned short u){ union{_Float16 f; unsigned short u;} c; c.u=u; return c.f; }

__device__ __forceinline__ void split8(float4 a, float4 b, half8& H, half8& L){
    _Float16 h;
    h=(_Float16)a.x; H[0]=h; L[0]=(_Float16)(a.x-(float)h);
    h=(_Float16)a.y; H[1]=h; L[1]=(_Float16)(a.y-(float)h);
    h=(_Float16)a.z; H[2]=h; L[2]=(_Float16)(a.z-(float)h);
    h=(_Float16)a.w; H[3]=h; L[3]=(_Float16)(a.w-(float)h);
    h=(_Float16)b.x; H[4]=h; L[4]=(_Float16)(b.x-(float)h);
    h=(_Float16)b.y; H[5]=h; L[5]=(_Float16)(b.y-(float)h);
    h=(_Float16)b.z; H[6]=h; L[6]=(_Float16)(b.z-(float)h);
    h=(_Float16)b.w; H[7]=h; L[7]=(_Float16)(b.w-(float)h);
}
__device__ __forceinline__ void unpack8(uint4 a, uint4 b, half8& H, half8& L){
    H[0]=b2h((unsigned short)(a.x>>16)); L[0]=b2h((unsigned short)(a.x&0xffffu));
    H[1]=b2h((unsigned short)(a.y>>16)); L[1]=b2h((unsigned short)(a.y&0xffffu));
    H[2]=b2h((unsigned short)(a.z>>16)); L[2]=b2h((unsigned short)(a.z&0xffffu));
    H[3]=b2h((unsigned short)(a.w>>16)); L[3]=b2h((unsigned short)(a.w&0xffffu));
    H[4]=b2h((unsigned short)(b.x>>16)); L[4]=b2h((unsigned short)(b.x&0xffffu));
    H[5]=b2h((unsigned short)(b.y>>16)); L[5]=b2h((unsigned short)(b.y&0xffffu));
    H[6]=b2h((unsigned short)(b.z>>16)); L[6]=b2h((unsigned short)(b.z&0xffffu));
    H[7]=b2h((unsigned short)(b.w>>16)); L[7]=b2h((unsigned short)(b.w&0xffffu));
}

// B fragment -> registers: lane(quad,ln) element e = W[kt*32+quad*8+e][col], hi/lo split.
// Literal indices only (no dynamic vector indexing -> no scratch demotion).
#define LDBE(e) { int r = kt*32 + quad*8 + (e); \
    float v = (r < R0) ? Wa[r*256 + col] : Wb[(r-R0)*256 + col]; \
    _Float16 hh = (_Float16)v; H[e] = hh; L[e] = (_Float16)(v - (float)hh); }
__device__ __forceinline__ void loadB(const float* __restrict__ Wa, const float* __restrict__ Wb,
                                      int R0, int kt, int quad, int col, half8& H, half8& L){
    LDBE(0) LDBE(1) LDBE(2) LDBE(3) LDBE(4) LDBE(5) LDBE(6) LDBE(7)
}

// 3-MFMA hi/lo split step (drop lo*lo)
#define K3(ah_, al_, Bh_, Bl_, acc_) { \
    acc_ = MFMA16(ah_, Bh_, acc_); acc_ = MFMA16(al_, Bh_, acc_); acc_ = MFMA16(ah_, Bl_, acc_); }

// C tile -> sG: row = rowbase + reg, col = nt*16 + ln
#define WRC2(acc_, rowbase, nt_) { int _b=(rowbase)*SGP + (nt_)*16 + ln; \
    sG[_b]=(acc_).x; sG[_b+SGP]=(acc_).y; sG[_b+2*SGP]=(acc_).z; sG[_b+3*SGP]=(acc_).w; }

__device__ __forceinline__ void atomicMaxF(float* addr, float v) {
    if (v >= 0.f) atomicMax((int*)addr, __float_as_int(v));
    else          atomicMin((unsigned int*)addr, __float_as_uint(v));
}

// ================= LSTM layer 0 =================
// block 512 = 8 waves, 32 seqs/block. A = [x_t(K=32) | h(K=64)] M=32, B(96x256) in REGISTERS.
// wave wv: n-tiles {2wv, 2wv+1}, both m-tiles -> 4 accs, 18 MFMAs. 2 barriers/timestep.
__global__ __launch_bounds__(512) void k_lstm0(
    const float* __restrict__ x, const float* __restrict__ Wih, const float* __restrict__ Whh,
    const float* __restrict__ bih, const float* __restrict__ bhh,
    unsigned int* __restrict__ hseq, float* __restrict__ hS, float* __restrict__ cS,
    int t0, int tc, int C)
{
    __shared__ float sG[32 * SGP];      // gate pre-activations, 32 x 256 (+pad)
    __shared__ float sHlin[32 * SHP];   // h_t fp32, padded pitch

    const int tid = threadIdx.x, lane = tid & 63, wv = tid >> 6;
    const int quad = lane >> 4, ln = lane & 15;
    const int nt0 = wv * 2, nt1 = wv * 2 + 1;
    const int k = tid & 63, sg = tid >> 6;
    const int n0 = blockIdx.x * 32;

    // persistent B fragments (3 kt x 2 nt x hi/lo = 12 half8 = 48 VGPR)
    half8 b0ah,b0al,b0bh,b0bl, b1ah,b1al,b1bh,b1bl, b2ah,b2al,b2bh,b2bl;
    {
        int colA = nt0*16 + ln, colB = nt1*16 + ln;
        loadB(Wih,Whh,32,0,quad,colA,b0ah,b0al); loadB(Wih,Whh,32,0,quad,colB,b0bh,b0bl);
        loadB(Wih,Whh,32,1,quad,colA,b1ah,b1al); loadB(Wih,Whh,32,1,quad,colB,b1bh,b1bl);
        loadB(Wih,Whh,32,2,quad,colA,b2ah,b2al); loadB(Wih,Whh,32,2,quad,colB,b2bh,b2bl);
    }
    const float bbA = bih[nt0*16+ln] + bhh[nt0*16+ln];
    const float bbB = bih[nt1*16+ln] + bhh[nt1*16+ln];
    const bool save = (t0 + tc < Tt);

    float c0, c1, c2, c3;
    if (t0 == 0) {
        c0 = c1 = c2 = c3 = 0.f;
        sHlin[sg*SHP+k] = 0.f; sHlin[(sg+8)*SHP+k] = 0.f;
        sHlin[(sg+16)*SHP+k] = 0.f; sHlin[(sg+24)*SHP+k] = 0.f;
    } else {
        c0 = cS[(size_t)(n0+sg)*HID+k];    c1 = cS[(size_t)(n0+sg+8)*HID+k];
        c2 = cS[(size_t)(n0+sg+16)*HID+k]; c3 = cS[(size_t)(n0+sg+24)*HID+k];
        sHlin[sg*SHP+k]      = hS[(size_t)(n0+sg)*HID+k];
        sHlin[(sg+8)*SHP+k]  = hS[(size_t)(n0+sg+8)*HID+k];
        sHlin[(sg+16)*SHP+k] = hS[(size_t)(n0+sg+16)*HID+k];
        sHlin[(sg+24)*SHP+k] = hS[(size_t)(n0+sg+24)*HID+k];
    }
    __syncthreads();

    for (int tt = 0; tt < tc; ++tt) {
        const int t = t0 + tt;
        // x frags: lane(quad,ln) of m-tile fid reads x[n0+fid*16+ln][quad*8 .. +7]
        const float* xr0 = x + (size_t)(n0+ln)    * (Tt*INP) + t*INP + quad*8;
        const float* xr1 = x + (size_t)(n0+16+ln) * (Tt*INP) + t*INP + quad*8;
        float4 xa0 = *(const float4*)xr0, xb0 = *(const float4*)(xr0+4);
        float4 xa1 = *(const float4*)xr1, xb1 = *(const float4*)(xr1+4);
        half8 xf0h,xf0l,xf1h,xf1l;
        split8(xa0,xb0,xf0h,xf0l); split8(xa1,xb1,xf1h,xf1l);
        // h frags from sHlin (2 kgrp x 2 fid)
        const float* p00 = &sHlin[ln*SHP + quad*8];
        const float* p01 = &sHlin[(16+ln)*SHP + quad*8];
        const float* p10 = &sHlin[ln*SHP + 32 + quad*8];
        const float* p11 = &sHlin[(16+ln)*SHP + 32 + quad*8];
        float4 a0 = *(const float4*)p00, a1 = *(const float4*)(p00+4);
        float4 a2 = *(const float4*)p01, a3 = *(const float4*)(p01+4);
        float4 a4 = *(const float4*)p10, a5 = *(const float4*)(p10+4);
        float4 a6 = *(const float4*)p11, a7 = *(const float4*)(p11+4);
        half8 h00h,h00l,h01h,h01l,h10h,h10l,h11h,h11l;
        split8(a0,a1,h00h,h00l); split8(a2,a3,h01h,h01l);
        split8(a4,a5,h10h,h10l); split8(a6,a7,h11h,h11l);

        f4 accA0 = {bbA,bbA,bbA,bbA}, accA1 = {bbB,bbB,bbB,bbB};
        f4 accB0 = {bbA,bbA,bbA,bbA}, accB1 = {bbB,bbB,bbB,bbB};
        // kt0 (x), kt1 (h kk0..31), kt2 (h kk32..63)
        K3(xf0h,xf0l,b0ah,b0al,accA0) K3(xf0h,xf0l,b0bh,b0bl,accA1)
        K3(xf1h,xf1l,b0ah,b0al,accB0) K3(xf1h,xf1l,b0bh,b0bl,accB1)
        K3(h00h,h00l,b1ah,b1al,accA0) K3(h00h,h00l,b1bh,b1bl,accA1)
        K3(h01h,h01l,b1ah,b1al,accB0) K3(h01h,h01l,b1bh,b1bl,accB1)
        K3(h10h,h10l,b2ah,b2al,accA0) K3(h10h,h10l,b2bh,b2bl,accA1)
        K3(h11h,h11l,b2ah,b2al,accB0) K3(h11h,h11l,b2bh,b2bl,accB1)

        WRC2(accA0, quad*4,      nt0)  WRC2(accA1, quad*4,      nt1)
        WRC2(accB0, 16 + quad*4, nt0)  WRC2(accB1, 16 + quad*4, nt1)
        __syncthreads();   // B1: sG visible

        #define GSTEP0(ss, creg) { \
            int base = (ss)*SGP + k; \
            float iv = fsigm(sG[base]), fv = fsigm(sG[base+64]); \
            float gv = ftanh(sG[base+128]), ov = fsigm(sG[base+192]); \
            creg = fv*creg + iv*gv; float hv = ov*ftanh(creg); \
            sHlin[(ss)*SHP + k] = hv; \
            _Float16 hh = (_Float16)hv, hl = (_Float16)(hv - (float)hh); \
            hseq[((size_t)(n0+(ss))*C + tt)*HID + k] = ((unsigned)h2b(hh)<<16) | (unsigned)h2b(hl); \
            if (save && tt == tc-1) { hS[(size_t)(n0+(ss))*HID+k] = hv; cS[(size_t)(n0+(ss))*HID+k] = creg; } }
        GSTEP0(sg,      c0)
        GSTEP0(sg + 8,  c1)
        GSTEP0(sg + 16, c2)
        GSTEP0(sg + 24, c3)
        #undef GSTEP0
        __syncthreads();   // B2: sHlin/sG safe for next iteration
    }
}

// ================= LSTM layer 1 =================
// A = [h0_t(K=64, packed hi/lo uints) | h1(K=64)] M=32, B(128x256) in REGISTERS (16 half8).
__global__ __launch_bounds__(512) void k_lstm1(
    const unsigned int* __restrict__ hseq, const float* __restrict__ Wih, const float* __restrict__ Whh,
    const float* __restrict__ bih, const float* __restrict__ bhh,
    float* __restrict__ h1last, float* __restrict__ hS, float* __restrict__ cS,
    int t0, int tc, int C)
{
    __shared__ float sG[32 * SGP];
    __shared__ float sHlin[32 * SHP];

    const int tid = threadIdx.x, lane = tid & 63, wv = tid >> 6;
    const int quad = lane >> 4, ln = lane & 15;
    const int nt0 = wv * 2, nt1 = wv * 2 + 1;
    const int k = tid & 63, sg = tid >> 6;
    const int n0 = blockIdx.x * 32;

    half8 b0ah,b0al,b0bh,b0bl, b1ah,b1al,b1bh,b1bl;
    half8 b2ah,b2al,b2bh,b2bl, b3ah,b3al,b3bh,b3bl;
    {
        int colA = nt0*16 + ln, colB = nt1*16 + ln;
        loadB(Wih,Whh,64,0,quad,colA,b0ah,b0al); loadB(Wih,Whh,64,0,quad,colB,b0bh,b0bl);
        loadB(Wih,Whh,64,1,quad,colA,b1ah,b1al); loadB(Wih,Whh,64,1,quad,colB,b1bh,b1bl);
        loadB(Wih,Whh,64,2,quad,colA,b2ah,b2al); loadB(Wih,Whh,64,2,quad,colB,b2bh,b2bl);
        loadB(Wih,Whh,64,3,quad,colA,b3ah,b3al); loadB(Wih,Whh,64,3,quad,colB,b3bh,b3bl);
    }
    const float bbA = bih[nt0*16+ln] + bhh[nt0*16+ln];
    const float bbB = bih[nt1*16+ln] + bhh[nt1*16+ln];
    const bool save = (t0 + tc < Tt);

    float c0, c1, c2, c3;
    if (t0 == 0) {
        c0 = c1 = c2 = c3 = 0.f;
        sHlin[sg*SHP+k] = 0.f; sHlin[(sg+8)*SHP+k] = 0.f;
        sHlin[(sg+16)*SHP+k] = 0.f; sHlin[(sg+24)*SHP+k] = 0.f;
    } else {
        c0 = cS[(size_t)(n0+sg)*HID+k];    c1 = cS[(size_t)(n0+sg+8)*HID+k];
        c2 = cS[(size_t)(n0+sg+16)*HID+k]; c3 = cS[(size_t)(n0+sg+24)*HID+k];
        sHlin[sg*SHP+k]      = hS[(size_t)(n0+sg)*HID+k];
        sHlin[(sg+8)*SHP+k]  = hS[(size_t)(n0+sg+8)*HID+k];
        sHlin[(sg+16)*SHP+k] = hS[(size_t)(n0+sg+16)*HID+k];
        sHlin[(sg+24)*SHP+k] = hS[(size_t)(n0+sg+24)*HID+k];
    }
    __syncthreads();

    for (int tt = 0; tt < tc; ++tt) {
        const int t = t0 + tt;
        // x frags (h0, packed) direct from global
        const unsigned* hp0 = hseq + ((size_t)(n0+ln)*C + tt)*HID + quad*8;
        const unsigned* hp1 = hseq + ((size_t)(n0+16+ln)*C + tt)*HID + quad*8;
        uint4 u0a = *(const uint4*)hp0,      u0b = *(const uint4*)(hp0+4);
        uint4 u1a = *(const uint4*)hp1,      u1b = *(const uint4*)(hp1+4);
        uint4 u2a = *(const uint4*)(hp0+32), u2b = *(const uint4*)(hp0+36);
        uint4 u3a = *(const uint4*)(hp1+32), u3b = *(const uint4*)(hp1+36);
        half8 x00h,x00l,x01h,x01l,x10h,x10l,x11h,x11l;
        unpack8(u0a,u0b,x00h,x00l); unpack8(u1a,u1b,x01h,x01l);
        unpack8(u2a,u2b,x10h,x10l); unpack8(u3a,u3b,x11h,x11l);
        // h frags from sHlin
        const float* p00 = &sHlin[ln*SHP + quad*8];
        const float* p01 = &sHlin[(16+ln)*SHP + quad*8];
        const float* p10 = &sHlin[ln*SHP + 32 + quad*8];
        const float* p11 = &sHlin[(16+ln)*SHP + 32 + quad*8];
        float4 a0 = *(const float4*)p00, a1 = *(const float4*)(p00+4);
        float4 a2 = *(const float4*)p01, a3 = *(const float4*)(p01+4);
        float4 a4 = *(const float4*)p10, a5 = *(const float4*)(p10+4);
        float4 a6 = *(const float4*)p11, a7 = *(const float4*)(p11+4);
        half8 h00h,h00l,h01h,h01l,h10h,h10l,h11h,h11l;
        split8(a0,a1,h00h,h00l); split8(a2,a3,h01h,h01l);
        split8(a4,a5,h10h,h10l); split8(a6,a7,h11h,h11l);

        f4 accA0 = {bbA,bbA,bbA,bbA}, accA1 = {bbB,bbB,bbB,bbB};
        f4 accB0 = {bbA,bbA,bbA,bbA}, accB1 = {bbB,bbB,bbB,bbB};
        // kt0/kt1 = x (h0), kt2/kt3 = h1
        K3(x00h,x00l,b0ah,b0al,accA0) K3(x00h,x00l,b0bh,b0bl,accA1)
        K3(x01h,x01l,b0ah,b0al,accB0) K3(x01h,x01l,b0bh,b0bl,accB1)
        K3(x10h,x10l,b1ah,b1al,accA0) K3(x10h,x10l,b1bh,b1bl,accA1)
        K3(x11h,x11l,b1ah,b1al,accB0) K3(x11h,x11l,b1bh,b1bl,accB1)
        K3(h00h,h00l,b2ah,b2al,accA0) K3(h00h,h00l,b2bh,b2bl,accA1)
        K3(h01h,h01l,b2ah,b2al,accB0) K3(h01h,h01l,b2bh,b2bl,accB1)
        K3(h10h,h10l,b3ah,b3al,accA0) K3(h10h,h10l,b3bh,b3bl,accA1)
        K3(h11h,h11l,b3ah,b3al,accB0) K3(h11h,h11l,b3bh,b3bl,accB1)

        WRC2(accA0, quad*4,      nt0)  WRC2(accA1, quad*4,      nt1)
        WRC2(accB0, 16 + quad*4, nt0)  WRC2(accB1, 16 + quad*4, nt1)
        __syncthreads();   // B1

        #define GSTEP1(ss, creg) { \
            int base = (ss)*SGP + k; \
            float iv = fsigm(sG[base]), fv = fsigm(sG[base+64]); \
            float gv = ftanh(sG[base+128]), ov = fsigm(sG[base+192]); \
            creg = fv*creg + iv*gv; float hv = ov*ftanh(creg); \
            sHlin[(ss)*SHP + k] = hv; \
            if (t == Tt-1) h1last[(size_t)(n0+(ss))*HID + k] = hv; \
            if (save && tt == tc-1) { hS[(size_t)(n0+(ss))*HID+k] = hv; cS[(size_t)(n0+(ss))*HID+k] = creg; } }
        GSTEP1(sg,      c0)
        GSTEP1(sg + 8,  c1)
        GSTEP1(sg + 16, c2)
        GSTEP1(sg + 24, c3)
        #undef GSTEP1
        __syncthreads();   // B2
    }
}

// ---------------- GAT1 projection ----------------
__global__ __launch_bounds__(256) void k_gproj1(
    const float* __restrict__ hl, const float* __restrict__ W1,
    const float* __restrict__ as1, const float* __restrict__ ad1,
    float* __restrict__ H1, float* __restrict__ a_s, float* __restrict__ a_d)
{
    __shared__ float sh[64];
    const int n = blockIdx.x, tid = threadIdx.x;
    if (tid < 64) sh[tid] = hl[(size_t)n * 64 + tid];
    __syncthreads();
    float acc = 0.f;
    #pragma unroll 8
    for (int j = 0; j < 64; ++j) acc += sh[j] * W1[j * 256 + tid];
    H1[(size_t)n * 256 + tid] = acc;
    float ls = acc * as1[tid], ld = acc * ad1[tid];
    #pragma unroll
    for (int off = 32; off >= 1; off >>= 1) { ls += __shfl_down(ls, off); ld += __shfl_down(ld, off); }
    if ((tid & 63) == 0) { a_s[n * 4 + (tid >> 6)] = ls; a_d[n * 4 + (tid >> 6)] = ld; }
}

// ---------------- edge max (4 heads) ----------------
__global__ void k_emax1(const int* __restrict__ ei, const float* __restrict__ a_s,
                        const float* __restrict__ a_d, float* __restrict__ m, int E, int Et)
{
    int idx = blockIdx.x * blockDim.x + threadIdx.x;
    if (idx >= Et * 4) return;
    int e = idx >> 2, h = idx & 3;
    int s, d;
    if (e < E) { s = ei[e]; d = ei[E + e]; } else { s = d = e - E; }
    float a = a_s[s * 4 + h] + a_d[d * 4 + h];
    float l = a > 0.f ? a : NEG * a;
    atomicMaxF(&m[d * 4 + h], l);
}

// ---------------- edge scatter (4 heads x 64) ----------------
__global__ __launch_bounds__(256) void k_escat1(
    const int* __restrict__ ei, const float* __restrict__ a_s, const float* __restrict__ a_d,
    const float* __restrict__ m, float* __restrict__ ssum,
    const float* __restrict__ H1, float* __restrict__ un, int E, int Et)
{
    int e = blockIdx.x;
    int tid = threadIdx.x, h = tid >> 6;
    int s, d;
    if (e < E) { s = ei[e]; d = ei[E + e]; } else { s = d = e - E; }
    float a = a_s[s * 4 + h] + a_d[d * 4 + h];
    float l = a > 0.f ? a : NEG * a;
    float ev = expf(l - m[d * 4 + h]);
    if ((tid & 63) == 0) atomicAdd(&ssum[d * 4 + h], ev);
    atomicAdd(&un[(size_t)d * 256 + tid], ev * H1[(size_t)s * 256 + tid]);
}

// ---------------- GAT1 finalize ----------------
__global__ void k_efin1(float* __restrict__ un, const float* __restrict__ ssum,
                        const float* __restrict__ b1, int N)
{
    int idx = blockIdx.x * blockDim.x + threadIdx.x;
    if (idx >= N * 256) return;
    int n = idx >> 8, kk = idx & 255, h = kk >> 6;
    float v = un[idx] / ssum[n * 4 + h] + b1[kk];
    un[idx] = v > 0.f ? v : 0.f;
}

// ---------------- GAT2 projection ----------------
__global__ __launch_bounds__(256) void k_gproj2(
    const float* __restrict__ h2, const float* __restrict__ W2,
    const float* __restrict__ as2, const float* __restrict__ ad2,
    float* __restrict__ H2, float* __restrict__ a2s, float* __restrict__ a2d)
{
    __shared__ float sh2[4][256];
    const int tid = threadIdx.x;
    const int n0 = blockIdx.x * 4;
    for (int idx = tid; idx < 1024; idx += 256)
        sh2[idx >> 8][idx & 255] = h2[(size_t)(n0 + (idx >> 8)) * 256 + (idx & 255)];
    __syncthreads();
    int w = tid >> 6, L = tid & 63, c = L & 31, half = L >> 5;
    float acc = 0.f;
    #pragma unroll 8
    for (int j = 0; j < 128; ++j) acc += sh2[w][half * 128 + j] * W2[(half * 128 + j) * 32 + c];
    acc += __shfl_down(acc, 32);
    float ls = 0.f, ld = 0.f;
    if (L < 32) {
        H2[(size_t)(n0 + w) * 32 + c] = acc;
        ls = acc * as2[c]; ld = acc * ad2[c];
    }
    #pragma unroll
    for (int off = 16; off >= 1; off >>= 1) { ls += __shfl_down(ls, off); ld += __shfl_down(ld, off); }
    if (L == 0) { a2s[n0 + w] = ls; a2d[n0 + w] = ld; }
}

// ---------------- edge max (1 head) ----------------
__global__ void k_emax2(const int* __restrict__ ei, const float* __restrict__ a_s,
                        const float* __restrict__ a_d, float* __restrict__ m, int E, int Et)
{
    int e = blockIdx.x * blockDim.x + threadIdx.x;
    if (e >= Et) return;
    int s, d;
    if (e < E) { s = ei[e]; d = ei[E + e]; } else { s = d = e - E; }
    float a = a_s[s] + a_d[d];
    float l = a > 0.f ? a : NEG * a;
    atomicMaxF(&m[d], l);
}

// ---------------- edge scatter (32 cols) ----------------
__global__ __launch_bounds__(256) void k_escat2(
    const int* __restrict__ ei, const float* __restrict__ a_s, const float* __restrict__ a_d,
    const float* __restrict__ m, float* __restrict__ ssum,
    const float* __restrict__ H2, float* __restrict__ outp, int E, int Et)
{
    int idx = blockIdx.x * blockDim.x + threadIdx.x;
    if (idx >= Et * 32) return;
    int e = idx >> 5, c = idx & 31;
    int s, d;
    if (e < E) { s = ei[e]; d = ei[E + e]; } else { s = d = e - E; }
    float a = a_s[s] + a_d[d];
    float l = a > 0.f ? a : NEG * a;
    float ev = expf(l - m[d]);
    if (c == 0) atomicAdd(&ssum[d], ev);
    atomicAdd(&outp[(size_t)d * 32 + c], ev * H2[(size_t)s * 32 + c]);
}

// ---------------- GAT2 finalize ----------------
__global__ void k_efin2(float* __restrict__ outp, const float* __restrict__ ssum,
                        const float* __restrict__ b2, int N)
{
    int idx = blockIdx.x * blockDim.x + threadIdx.x;
    if (idx >= N * 32) return;
    outp[idx] = outp[idx] / ssum[idx >> 5] + b2[idx & 31];
}

__global__ void k_neginf(float* __restrict__ p, int n)
{
    int idx = blockIdx.x * blockDim.x + threadIdx.x;
    if (idx < n) p[idx] = -INFINITY;
}

static inline int cdiv(long long a, long long b) { return (int)((a + b - 1) / b); }

extern "C" void kernel_launch(void* const* d_in, const int* in_sizes, int n_in,
                              void* d_out, int out_size, void* d_ws, size_t ws_size,
                              hipStream_t stream)
{
    const float* x    = (const float*)d_in[0];
    const int*   ei   = (const int*)d_in[1];
    const float* Wih0 = (const float*)d_in[2];
    const float* Whh0 = (const float*)d_in[3];
    const float* bih0 = (const float*)d_in[4];
    const float* bhh0 = (const float*)d_in[5];
    const float* Wih1 = (const float*)d_in[6];
    const float* Whh1 = (const float*)d_in[7];
    const float* bih1 = (const float*)d_in[8];
    const float* bhh1 = (const float*)d_in[9];
    const float* W1   = (const float*)d_in[10];
    const float* as1  = (const float*)d_in[11];
    const float* ad1  = (const float*)d_in[12];
    const float* b1   = (const float*)d_in[13];
    const float* W2   = (const float*)d_in[14];
    const float* as2  = (const float*)d_in[15];
    const float* ad2  = (const float*)d_in[16];
    const float* b2   = (const float*)d_in[17];
    float* outp = (float*)d_out;

    const int N  = in_sizes[0] / (Tt * INP);
    const int E  = in_sizes[1] / 2;
    const int Et = E + N;
    const int NB = N / 32;                  // 32 seqs per LSTM block

    float* ws = (float*)d_ws;
    const size_t N64 = (size_t)N * 64;

    float* h1last = ws;               // N*64, persists LSTM -> GAT
    float* rA = ws + N64;

    // region A (LSTM)
    float* h0s = rA;
    float* c0s = rA + N64;
    float* h1s = rA + 2 * N64;
    float* c1s = rA + 3 * N64;
    unsigned int* h0chunk = (unsigned int*)(rA + 4 * N64);    // N*C*64 packed (hi,lo) f16

    long long availChunkRows = (long long)(ws_size / 4) - (long long)(5 * N64);
    int C = (int)(availChunkRows / (long long)N64);
    if (C > Tt) C = Tt;
    if (C < 1) C = 1;

    // region B (GAT) — overlays region A
    float* H1   = rA;                         // N*256
    float* un1  = H1 + (size_t)N * 256;       // N*256 (becomes h2)
    float* H2   = un1 + (size_t)N * 256;      // N*32
    float* as1p = H2 + (size_t)N * 32;        // N*4
    float* ad1p = as1p + (size_t)N * 4;
    float* m1   = ad1p + (size_t)N * 4;
    float* s1   = m1 + (size_t)N * 4;
    float* a2s  = s1 + (size_t)N * 4;         // N
    float* a2d  = a2s + N;
    float* m2   = a2d + N;
    float* s2   = m2 + N;

    // ---- LSTM (chunked over T) ----
    for (int t0 = 0; t0 < Tt; t0 += C) {
        int tc = Tt - t0 < C ? Tt - t0 : C;
        k_lstm0<<<dim3(NB), dim3(512), 0, stream>>>(x, Wih0, Whh0, bih0, bhh0,
                                                    h0chunk, h0s, c0s, t0, tc, C);
        k_lstm1<<<dim3(NB), dim3(512), 0, stream>>>(h0chunk, Wih1, Whh1, bih1, bhh1,
                                                    h1last, h1s, c1s, t0, tc, C);
    }

    // ---- init GAT accumulators ----
    hipMemsetAsync(un1, 0, (size_t)N * 256 * 4, stream);
    hipMemsetAsync(s1, 0, (size_t)N * 4 * 4, stream);
    hipMemsetAsync(s2, 0, (size_t)N * 4, stream);
    hipMemsetAsync(outp, 0, (size_t)N * 32 * 4, stream);
    k_neginf<<<cdiv((long long)N * 4, 256), 256, 0, stream>>>(m1, N * 4);
    k_neginf<<<cdiv(N, 256), 256, 0, stream>>>(m2, N);

    // ---- GAT layer 1 ----
    k_gproj1<<<dim3(N), dim3(256), 0, stream>>>(h1last, W1, as1, ad1, H1, as1p, ad1p);
    k_emax1<<<cdiv((long long)Et * 4, 256), 256, 0, stream>>>(ei, as1p, ad1p, m1, E, Et);
    k_escat1<<<dim3(Et), dim3(256), 0, stream>>>(ei, as1p, ad1p, m1, s1, H1, un1, E, Et);
    k_efin1<<<cdiv((long long)N * 256, 256), 256, 0, stream>>>(un1, s1, b1, N);

    // ---- GAT layer 2 ----
    k_gproj2<<<dim3(N / 4), dim3(256), 0, stream>>>(un1, W2, as2, ad2, H2, a2s, a2d);
    k_emax2<<<cdiv(Et, 256), 256, 0, stream>>>(ei, a2s, a2d, m2, E, Et);
    k_escat2<<<cdiv((long long)Et * 32, 256), 256, 0, stream>>>(ei, a2s, a2d, m2, s2, H2, outp, E, Et);
    k_efin2<<<cdiv((long long)N * 32, 256), 256, 0, stream>>>(outp, s2, b2, N);
}

// Round 6
// 773.176 us; speedup vs baseline: 119.2162x; 1.7007x over previous
//
#include <hip/hip_runtime.h>
#include <math.h>

#define Tt  30
#define INP 32
#define HID 64
#define NEG 0.2f
#define SHP 68      // sH pitch (floats): +4 pad
#define SGP 260     // sG pitch (floats)

typedef __attribute__((ext_vector_type(8))) _Float16 half8;
typedef __attribute__((ext_vector_type(4))) float    f4;

#define MFMA16(a,b,c) __builtin_amdgcn_mfma_f32_16x16x32_f16((a),(b),(c),0,0,0)

__device__ __forceinline__ float fsigm(float v){ return __builtin_amdgcn_rcpf(1.f + __expf(-v)); }
__device__ __forceinline__ float ftanh(float v){ return 2.f * __builtin_amdgcn_rcpf(1.f + __expf(-2.f*v)) - 1.f; }

__device__ __forceinline__ void split8(float4 a, float4 b, half8& H, half8& L){
    _Float16 h;
    h=(_Float16)a.x; H[0]=h; L[0]=(_Float16)(a.x-(float)h);
    h=(_Float16)a.y; H[1]=h; L[1]=(_Float16)(a.y-(float)h);
    h=(_Float16)a.z; H[2]=h; L[2]=(_Float16)(a.z-(float)h);
    h=(_Float16)a.w; H[3]=h; L[3]=(_Float16)(a.w-(float)h);
    h=(_Float16)b.x; H[4]=h; L[4]=(_Float16)(b.x-(float)h);
    h=(_Float16)b.y; H[5]=h; L[5]=(_Float16)(b.y-(float)h);
    h=(_Float16)b.z; H[6]=h; L[6]=(_Float16)(b.z-(float)h);
    h=(_Float16)b.w; H[7]=h; L[7]=(_Float16)(b.w-(float)h);
}

// B fragment -> registers (literal indices only; no dynamic vector indexing)
#define LDBE(e) { int r = kt*32 + quad*8 + (e); \
    float v = (r < R0) ? Wa[r*256 + col] : Wb[(r-R0)*256 + col]; \
    _Float16 hh = (_Float16)v; H[e] = hh; L[e] = (_Float16)(v - (float)hh); }
__device__ __forceinline__ void loadB(const float* __restrict__ Wa, const float* __restrict__ Wb,
                                      int R0, int kt, int quad, int col, half8& H, half8& L){
    LDBE(0) LDBE(1) LDBE(2) LDBE(3) LDBE(4) LDBE(5) LDBE(6) LDBE(7)
}

#define K3(ah_, al_, Bh_, Bl_, acc_) { \
    acc_ = MFMA16(ah_, Bh_, acc_); acc_ = MFMA16(al_, Bh_, acc_); acc_ = MFMA16(ah_, Bl_, acc_); }

#define WRC2(acc_, rowbase, nt_) { int _b=(rowbase)*SGP + (nt_)*16 + ln; \
    sG[_b]=(acc_).x; sG[_b+SGP]=(acc_).y; sG[_b+2*SGP]=(acc_).z; sG[_b+3*SGP]=(acc_).w; }

// ================= FUSED 2-layer LSTM =================
// block 512 = 8 waves, 32 seqs/block, grid N/32. Both layers' weights in registers
// (L0: 12 half8 = 48 VGPR, L1: 16 half8 = 64 VGPR). h0 handoff via LDS — the 30-step
// loop has ZERO global stores (except h1last at t=29) so per-timestep barriers drain
// only lgkm (round-5 lesson: global ops inside barriered loop serialize on vmcnt(0)).
__global__ __launch_bounds__(512, 2) void k_lstm_fused(
    const float* __restrict__ x,
    const float* __restrict__ Wih0, const float* __restrict__ Whh0,
    const float* __restrict__ bih0, const float* __restrict__ bhh0,
    const float* __restrict__ Wih1, const float* __restrict__ Whh1,
    const float* __restrict__ bih1, const float* __restrict__ bhh1,
    float* __restrict__ h1last)
{
    __shared__ float sG[32 * SGP];      // gate pre-activations (shared by both layers)
    __shared__ float sH0[32 * SHP];     // h0_t fp32
    __shared__ float sH1[32 * SHP];     // h1_t fp32

    const int tid = threadIdx.x, lane = tid & 63, wv = tid >> 6;
    const int quad = lane >> 4, ln = lane & 15;
    const int nt0 = wv * 2, nt1 = wv * 2 + 1;
    const int k = tid & 63, sg = tid >> 6;
    const int n0 = blockIdx.x * 32;

    // ---- L0 weights in regs: 3 kt x {colA,colB} x {hi,lo} ----
    half8 p0ah,p0al,p0bh,p0bl, p1ah,p1al,p1bh,p1bl, p2ah,p2al,p2bh,p2bl;
    // ---- L1 weights in regs: 4 kt x {colA,colB} x {hi,lo} ----
    half8 q0ah,q0al,q0bh,q0bl, q1ah,q1al,q1bh,q1bl;
    half8 q2ah,q2al,q2bh,q2bl, q3ah,q3al,q3bh,q3bl;
    {
        int colA = nt0*16 + ln, colB = nt1*16 + ln;
        loadB(Wih0,Whh0,32,0,quad,colA,p0ah,p0al); loadB(Wih0,Whh0,32,0,quad,colB,p0bh,p0bl);
        loadB(Wih0,Whh0,32,1,quad,colA,p1ah,p1al); loadB(Wih0,Whh0,32,1,quad,colB,p1bh,p1bl);
        loadB(Wih0,Whh0,32,2,quad,colA,p2ah,p2al); loadB(Wih0,Whh0,32,2,quad,colB,p2bh,p2bl);
        loadB(Wih1,Whh1,64,0,quad,colA,q0ah,q0al); loadB(Wih1,Whh1,64,0,quad,colB,q0bh,q0bl);
        loadB(Wih1,Whh1,64,1,quad,colA,q1ah,q1al); loadB(Wih1,Whh1,64,1,quad,colB,q1bh,q1bl);
        loadB(Wih1,Whh1,64,2,quad,colA,q2ah,q2al); loadB(Wih1,Whh1,64,2,quad,colB,q2bh,q2bl);
        loadB(Wih1,Whh1,64,3,quad,colA,q3ah,q3al); loadB(Wih1,Whh1,64,3,quad,colB,q3bh,q3bl);
    }
    const float bb0A = bih0[nt0*16+ln] + bhh0[nt0*16+ln];
    const float bb0B = bih0[nt1*16+ln] + bhh0[nt1*16+ln];
    const float bb1A = bih1[nt0*16+ln] + bhh1[nt0*16+ln];
    const float bb1B = bih1[nt1*16+ln] + bhh1[nt1*16+ln];

    float c00=0.f,c01=0.f,c02=0.f,c03=0.f;   // L0 cell state (4 seqs/thread)
    float c10=0.f,c11=0.f,c12=0.f,c13=0.f;   // L1
    for (int idx = tid; idx < 32*SHP; idx += 512) { sH0[idx] = 0.f; sH1[idx] = 0.f; }
    __syncthreads();

    for (int tt = 0; tt < Tt; ++tt) {
        // ---- A0 frags: x_t (global) + h0_{t-1} (sH0) ----
        const float* xr0 = x + (size_t)(n0+ln)    * (Tt*INP) + tt*INP + quad*8;
        const float* xr1 = x + (size_t)(n0+16+ln) * (Tt*INP) + tt*INP + quad*8;
        float4 xa0 = *(const float4*)xr0, xb0 = *(const float4*)(xr0+4);
        float4 xa1 = *(const float4*)xr1, xb1 = *(const float4*)(xr1+4);
        half8 xf0h,xf0l,xf1h,xf1l;
        split8(xa0,xb0,xf0h,xf0l); split8(xa1,xb1,xf1h,xf1l);
        {
            const float* p00 = &sH0[ln*SHP + quad*8];
            const float* p01 = &sH0[(16+ln)*SHP + quad*8];
            const float* p10 = &sH0[ln*SHP + 32 + quad*8];
            const float* p11 = &sH0[(16+ln)*SHP + 32 + quad*8];
            float4 a0 = *(const float4*)p00, a1 = *(const float4*)(p00+4);
            float4 a2 = *(const float4*)p01, a3 = *(const float4*)(p01+4);
            float4 a4 = *(const float4*)p10, a5 = *(const float4*)(p10+4);
            float4 a6 = *(const float4*)p11, a7 = *(const float4*)(p11+4);
            half8 h00h,h00l,h01h,h01l,h10h,h10l,h11h,h11l;
            split8(a0,a1,h00h,h00l); split8(a2,a3,h01h,h01l);
            split8(a4,a5,h10h,h10l); split8(a6,a7,h11h,h11l);

            f4 accA0 = {bb0A,bb0A,bb0A,bb0A}, accA1 = {bb0B,bb0B,bb0B,bb0B};
            f4 accB0 = {bb0A,bb0A,bb0A,bb0A}, accB1 = {bb0B,bb0B,bb0B,bb0B};
            K3(xf0h,xf0l,p0ah,p0al,accA0) K3(xf0h,xf0l,p0bh,p0bl,accA1)
            K3(xf1h,xf1l,p0ah,p0al,accB0) K3(xf1h,xf1l,p0bh,p0bl,accB1)
            K3(h00h,h00l,p1ah,p1al,accA0) K3(h00h,h00l,p1bh,p1bl,accA1)
            K3(h01h,h01l,p1ah,p1al,accB0) K3(h01h,h01l,p1bh,p1bl,accB1)
            K3(h10h,h10l,p2ah,p2al,accA0) K3(h10h,h10l,p2bh,p2bl,accA1)
            K3(h11h,h11l,p2ah,p2al,accB0) K3(h11h,h11l,p2bh,p2bl,accB1)

            WRC2(accA0, quad*4,      nt0)  WRC2(accA1, quad*4,      nt1)
            WRC2(accB0, 16 + quad*4, nt0)  WRC2(accB1, 16 + quad*4, nt1)
        }
        __syncthreads();   // B1: sG(L0) visible; sH0 reads done

        // ---- epilogue L0 -> sH0 (h0_t) ----
        #define GE0(ss, creg) { int _b = (ss)*SGP + k; \
            float iv=fsigm(sG[_b]), fv=fsigm(sG[_b+64]); \
            float gv=ftanh(sG[_b+128]), ov=fsigm(sG[_b+192]); \
            creg = fv*creg + iv*gv; sH0[(ss)*SHP + k] = ov*ftanh(creg); }
        GE0(sg, c00) GE0(sg+8, c01) GE0(sg+16, c02) GE0(sg+24, c03)
        #undef GE0
        __syncthreads();   // B2: sH0(h0_t) visible; sG(L0) reads done

        // ---- A1 frags: h0_t (sH0, kt0/kt1) + h1_{t-1} (sH1, kt2/kt3) ----
        {
            const float* r00 = &sH0[ln*SHP + quad*8];
            const float* r01 = &sH0[(16+ln)*SHP + quad*8];
            const float* r10 = &sH0[ln*SHP + 32 + quad*8];
            const float* r11 = &sH0[(16+ln)*SHP + 32 + quad*8];
            float4 a0 = *(const float4*)r00, a1 = *(const float4*)(r00+4);
            float4 a2 = *(const float4*)r01, a3 = *(const float4*)(r01+4);
            float4 a4 = *(const float4*)r10, a5 = *(const float4*)(r10+4);
            float4 a6 = *(const float4*)r11, a7 = *(const float4*)(r11+4);
            half8 x00h,x00l,x01h,x01l,x10h,x10l,x11h,x11l;
            split8(a0,a1,x00h,x00l); split8(a2,a3,x01h,x01l);
            split8(a4,a5,x10h,x10l); split8(a6,a7,x11h,x11l);

            const float* s00 = &sH1[ln*SHP + quad*8];
            const float* s01 = &sH1[(16+ln)*SHP + quad*8];
            const float* s10 = &sH1[ln*SHP + 32 + quad*8];
            const float* s11 = &sH1[(16+ln)*SHP + 32 + quad*8];
            float4 b0 = *(const float4*)s00, b1 = *(const float4*)(s00+4);
            float4 b2v = *(const float4*)s01, b3 = *(const float4*)(s01+4);
            float4 b4 = *(const float4*)s10, b5 = *(const float4*)(s10+4);
            float4 b6 = *(const float4*)s11, b7 = *(const float4*)(s11+4);
            half8 h00h,h00l,h01h,h01l,h10h,h10l,h11h,h11l;
            split8(b0,b1,h00h,h00l); split8(b2v,b3,h01h,h01l);
            split8(b4,b5,h10h,h10l); split8(b6,b7,h11h,h11l);

            f4 accA0 = {bb1A,bb1A,bb1A,bb1A}, accA1 = {bb1B,bb1B,bb1B,bb1B};
            f4 accB0 = {bb1A,bb1A,bb1A,bb1A}, accB1 = {bb1B,bb1B,bb1B,bb1B};
            K3(x00h,x00l,q0ah,q0al,accA0) K3(x00h,x00l,q0bh,q0bl,accA1)
            K3(x01h,x01l,q0ah,q0al,accB0) K3(x01h,x01l,q0bh,q0bl,accB1)
            K3(x10h,x10l,q1ah,q1al,accA0) K3(x10h,x10l,q1bh,q1bl,accA1)
            K3(x11h,x11l,q1ah,q1al,accB0) K3(x11h,x11l,q1bh,q1bl,accB1)
            K3(h00h,h00l,q2ah,q2al,accA0) K3(h00h,h00l,q2bh,q2bl,accA1)
            K3(h01h,h01l,q2ah,q2al,accB0) K3(h01h,h01l,q2bh,q2bl,accB1)
            K3(h10h,h10l,q3ah,q3al,accA0) K3(h10h,h10l,q3bh,q3bl,accA1)
            K3(h11h,h11l,q3ah,q3al,accB0) K3(h11h,h11l,q3bh,q3bl,accB1)

            WRC2(accA0, quad*4,      nt0)  WRC2(accA1, quad*4,      nt1)
            WRC2(accB0, 16 + quad*4, nt0)  WRC2(accB1, 16 + quad*4, nt1)
        }
        __syncthreads();   // B3: sG(L1) visible; sH0/sH1 reads done

        // ---- epilogue L1 -> sH1 (h1_t) ----
        #define GE1(ss, creg) { int _b = (ss)*SGP + k; \
            float iv=fsigm(sG[_b]), fv=fsigm(sG[_b+64]); \
            float gv=ftanh(sG[_b+128]), ov=fsigm(sG[_b+192]); \
            creg = fv*creg + iv*gv; float hv = ov*ftanh(creg); \
            sH1[(ss)*SHP + k] = hv; \
            if (tt == Tt-1) h1last[(size_t)(n0+(ss))*HID + k] = hv; }
        GE1(sg, c10) GE1(sg+8, c11) GE1(sg+16, c12) GE1(sg+24, c13)
        #undef GE1
        __syncthreads();   // B4: sH1 visible; sG(L1) reads done
    }
}

// ---------------- GAT1 projection ----------------
__global__ __launch_bounds__(256) void k_gproj1(
    const float* __restrict__ hl, const float* __restrict__ W1,
    const float* __restrict__ as1, const float* __restrict__ ad1,
    float* __restrict__ H1, float* __restrict__ a_s, float* __restrict__ a_d)
{
    __shared__ float sh[64];
    const int n = blockIdx.x, tid = threadIdx.x;
    if (tid < 64) sh[tid] = hl[(size_t)n * 64 + tid];
    __syncthreads();
    float acc = 0.f;
    #pragma unroll 8
    for (int j = 0; j < 64; ++j) acc += sh[j] * W1[j * 256 + tid];
    H1[(size_t)n * 256 + tid] = acc;
    float ls = acc * as1[tid], ld = acc * ad1[tid];
    #pragma unroll
    for (int off = 32; off >= 1; off >>= 1) { ls += __shfl_down(ls, off); ld += __shfl_down(ld, off); }
    if ((tid & 63) == 0) { a_s[n * 4 + (tid >> 6)] = ls; a_d[n * 4 + (tid >> 6)] = ld; }
}

// ---------------- GAT2 projection ----------------
__global__ __launch_bounds__(256) void k_gproj2(
    const float* __restrict__ h2, const float* __restrict__ W2,
    const float* __restrict__ as2, const float* __restrict__ ad2,
    float* __restrict__ H2, float* __restrict__ a2s, float* __restrict__ a2d)
{
    __shared__ float sh2[4][256];
    const int tid = threadIdx.x;
    const int n0 = blockIdx.x * 4;
    for (int idx = tid; idx < 1024; idx += 256)
        sh2[idx >> 8][idx & 255] = h2[(size_t)(n0 + (idx >> 8)) * 256 + (idx & 255)];
    __syncthreads();
    int w = tid >> 6, L = tid & 63, c = L & 31, half = L >> 5;
    float acc = 0.f;
    #pragma unroll 8
    for (int j = 0; j < 128; ++j) acc += sh2[w][half * 128 + j] * W2[(half * 128 + j) * 32 + c];
    acc += __shfl_down(acc, 32);
    float ls = 0.f, ld = 0.f;
    if (L < 32) {
        H2[(size_t)(n0 + w) * 32 + c] = acc;
        ls = acc * as2[c]; ld = acc * ad2[c];
    }
    #pragma unroll
    for (int off = 16; off >= 1; off >>= 1) { ls += __shfl_down(ls, off); ld += __shfl_down(ld, off); }
    if (L == 0) { a2s[n0 + w] = ls; a2d[n0 + w] = ld; }
}

// ================= edge bucketing (counting sort by dst) =================
__global__ void k_count(const int* __restrict__ ei, int* __restrict__ deg, int E, int Et)
{
    int e = blockIdx.x * blockDim.x + threadIdx.x;
    if (e >= Et) return;
    int d = (e < E) ? ei[E + e] : e - E;
    atomicAdd(&deg[d], 1);
}

__global__ __launch_bounds__(256) void k_scanA(const int* __restrict__ deg, int* __restrict__ off,
                                               int* __restrict__ csum, int N)
{
    __shared__ int sm[256];
    int b = blockIdx.x, tid = threadIdx.x, i = b * 256 + tid;
    int v = (i < N) ? deg[i] : 0;
    sm[tid] = v;
    __syncthreads();
    #pragma unroll
    for (int s = 1; s < 256; s <<= 1) {
        int t = (tid >= s) ? sm[tid - s] : 0;
        __syncthreads();
        sm[tid] += t;
        __syncthreads();
    }
    if (i < N) off[i] = sm[tid] - v;
    if (tid == 255) csum[b] = sm[255];
}

__global__ void k_scanB(int* __restrict__ csum, int NC)
{
    if (blockIdx.x == 0 && threadIdx.x == 0) {
        int run = 0;
        for (int b = 0; b < NC; ++b) { int t = csum[b]; csum[b] = run; run += t; }
    }
}

__global__ __launch_bounds__(256) void k_scanC(int* __restrict__ off, const int* __restrict__ csum, int N)
{
    int i = blockIdx.x * blockDim.x + threadIdx.x;
    if (i < N) off[i] += csum[blockIdx.x >> 0 ? (i >> 8) : (i >> 8)];
}

__global__ void k_fill(const int* __restrict__ ei, int* __restrict__ cursor,
                       int* __restrict__ elist, int E, int Et)
{
    int e = blockIdx.x * blockDim.x + threadIdx.x;
    if (e >= Et) return;
    int s, d;
    if (e < E) { s = ei[e]; d = ei[E + e]; } else { s = d = e - E; }
    int slot = atomicAdd(&cursor[d], 1);
    elist[slot] = s;
}

// ================= GAT1 gather: max+softmax+aggregate+bias+relu fused =================
// block = 256 (head h = tid>>6, channel c = tid&63) per destination node.
__global__ __launch_bounds__(256) void k_gat1(
    const int* __restrict__ off, const int* __restrict__ deg, const int* __restrict__ elist,
    const float* __restrict__ a_s, const float* __restrict__ a_d,
    const float* __restrict__ H1, const float* __restrict__ b1,
    float* __restrict__ h2)
{
    __shared__ float sMax[4];
    __shared__ int   sSrc[256];
    __shared__ float sAl[256 * 4];
    const int d = blockIdx.x, tid = threadIdx.x;
    const int h = tid >> 6, ln = tid & 63;
    const int base = off[d], n_e = deg[d];
    const float add = a_d[d * 4 + h];

    // pass 1: per-head max (wave h scans edges, lanes strided)
    float mx = -INFINITY;
    for (int e = ln; e < n_e; e += 64) {
        int s = elist[base + e];
        float a = a_s[s * 4 + h] + add;
        mx = fmaxf(mx, a > 0.f ? a : NEG * a);
    }
    #pragma unroll
    for (int o = 32; o >= 1; o >>= 1) mx = fmaxf(mx, __shfl_down(mx, o));
    if (ln == 0) sMax[h] = mx;
    __syncthreads();

    float acc = 0.f, asum = 0.f;
    for (int c0 = 0; c0 < n_e; c0 += 256) {
        int nc = min(256, n_e - c0);
        if (tid < nc) sSrc[tid] = elist[base + c0 + tid];
        __syncthreads();
        for (int idx = tid; idx < nc * 4; idx += 256) {
            int e = idx >> 2, hh = idx & 3;
            int s = sSrc[e];
            float a = a_s[s * 4 + hh] + a_d[d * 4 + hh];
            float l = a > 0.f ? a : NEG * a;
            sAl[idx] = __expf(l - sMax[hh]);
        }
        __syncthreads();
        for (int e = 0; e < nc; ++e) {
            float al = sAl[e * 4 + h];
            acc  += al * H1[(size_t)sSrc[e] * 256 + tid];
            asum += al;
        }
        __syncthreads();
    }
    float v = acc * __builtin_amdgcn_rcpf(asum) + b1[tid];
    h2[(size_t)d * 256 + tid] = v > 0.f ? v : 0.f;
}

// ================= GAT2 gather =================
// block = 64 (1 wave) per destination; channels 32, edges split across 2 half-waves.
__global__ __launch_bounds__(64) void k_gat2(
    const int* __restrict__ off, const int* __restrict__ deg, const int* __restrict__ elist,
    const float* __restrict__ a2s, const float* __restrict__ a2d,
    const float* __restrict__ H2, const float* __restrict__ b2,
    float* __restrict__ outp)
{
    const int d = blockIdx.x, lane = threadIdx.x;
    const int base = off[d], n_e = deg[d];
    const float add = a2d[d];

    float mx = -INFINITY;
    for (int e = lane; e < n_e; e += 64) {
        int s = elist[base + e];
        float a = a2s[s] + add;
        mx = fmaxf(mx, a > 0.f ? a : NEG * a);
    }
    #pragma unroll
    for (int o = 32; o >= 1; o >>= 1) mx = fmaxf(mx, __shfl_down(mx, o));
    mx = __shfl(mx, 0);

    const int half = lane >> 5, c = lane & 31;
    float acc = 0.f, asum = 0.f;
    for (int e = half; e < n_e; e += 2) {
        int s = elist[base + e];
        float a = a2s[s] + add;
        float l = a > 0.f ? a : NEG * a;
        float al = __expf(l - mx);
        acc  += al * H2[(size_t)s * 32 + c];
        asum += al;
    }
    acc  += __shfl_down(acc, 32);
    asum += __shfl_down(asum, 32);
    if (lane < 32) outp[(size_t)d * 32 + c] = acc * __builtin_amdgcn_rcpf(asum) + b2[c];
}

static inline int cdiv(long long a, long long b) { return (int)((a + b - 1) / b); }

extern "C" void kernel_launch(void* const* d_in, const int* in_sizes, int n_in,
                              void* d_out, int out_size, void* d_ws, size_t ws_size,
                              hipStream_t stream)
{
    const float* x    = (const float*)d_in[0];
    const int*   ei   = (const int*)d_in[1];
    const float* Wih0 = (const float*)d_in[2];
    const float* Whh0 = (const float*)d_in[3];
    const float* bih0 = (const float*)d_in[4];
    const float* bhh0 = (const float*)d_in[5];
    const float* Wih1 = (const float*)d_in[6];
    const float* Whh1 = (const float*)d_in[7];
    const float* bih1 = (const float*)d_in[8];
    const float* bhh1 = (const float*)d_in[9];
    const float* W1   = (const float*)d_in[10];
    const float* as1  = (const float*)d_in[11];
    const float* ad1  = (const float*)d_in[12];
    const float* b1   = (const float*)d_in[13];
    const float* W2   = (const float*)d_in[14];
    const float* as2  = (const float*)d_in[15];
    const float* ad2  = (const float*)d_in[16];
    const float* b2   = (const float*)d_in[17];
    float* outp = (float*)d_out;

    const int N  = in_sizes[0] / (Tt * INP);
    const int E  = in_sizes[1] / 2;
    const int Et = E + N;
    const int NC = cdiv(N, 256);

    float* ws = (float*)d_ws;
    float* h1last = ws;                          // N*64
    float* H1   = h1last + (size_t)N * 64;       // N*256
    float* h2   = H1 + (size_t)N * 256;          // N*256
    float* H2   = h2 + (size_t)N * 256;          // N*32
    float* as1p = H2 + (size_t)N * 32;           // N*4
    float* ad1p = as1p + (size_t)N * 4;          // N*4
    float* a2s  = ad1p + (size_t)N * 4;          // N
    float* a2d  = a2s + N;                       // N
    int* deg    = (int*)(a2d + N);               // N
    int* off    = deg + N;                       // N
    int* cursor = off + N;                       // N
    int* csum   = cursor + N;                    // NC
    int* elist  = csum + NC;                     // Et

    // ---- fused 2-layer LSTM (single dispatch, no chunking, no hseq round-trip) ----
    k_lstm_fused<<<dim3(N / 32), dim3(512), 0, stream>>>(
        x, Wih0, Whh0, bih0, bhh0, Wih1, Whh1, bih1, bhh1, h1last);

    // ---- bucket edges by destination (shared by both GAT layers) ----
    hipMemsetAsync(deg, 0, (size_t)N * 4, stream);
    k_count<<<cdiv(Et, 256), 256, 0, stream>>>(ei, deg, E, Et);
    k_scanA<<<NC, 256, 0, stream>>>(deg, off, csum, N);
    k_scanB<<<1, 1, 0, stream>>>(csum, NC);
    k_scanC<<<NC, 256, 0, stream>>>(off, csum, N);
    hipMemcpyAsync(cursor, off, (size_t)N * 4, hipMemcpyDeviceToDevice, stream);
    k_fill<<<cdiv(Et, 256), 256, 0, stream>>>(ei, cursor, elist, E, Et);

    // ---- GAT layer 1 (projection + fused gather) ----
    k_gproj1<<<dim3(N), dim3(256), 0, stream>>>(h1last, W1, as1, ad1, H1, as1p, ad1p);
    k_gat1<<<dim3(N), dim3(256), 0, stream>>>(off, deg, elist, as1p, ad1p, H1, b1, h2);

    // ---- GAT layer 2 ----
    k_gproj2<<<dim3(N / 4), dim3(256), 0, stream>>>(h2, W2, as2, ad2, H2, a2s, a2d);
    k_gat2<<<dim3(N), dim3(64), 0, stream>>>(off, deg, elist, a2s, a2d, H2, b2, outp);
}

// Round 7
// 743.894 us; speedup vs baseline: 123.9089x; 1.0394x over previous
//
#include <hip/hip_runtime.h>
#include <math.h>

#define Tt  30
#define INP 32
#define HID 64
#define NEG 0.2f
#define SHP 68      // packed-h pitch (uints): +4 pad
#define SGP 260     // sG pitch (floats)

typedef __attribute__((ext_vector_type(8))) _Float16 half8;
typedef __attribute__((ext_vector_type(4))) float    f4;

#define MFMA16(a,b,c) __builtin_amdgcn_mfma_f32_16x16x32_f16((a),(b),(c),0,0,0)

__device__ __forceinline__ float fsigm(float v){ return __builtin_amdgcn_rcpf(1.f + __expf(-v)); }
__device__ __forceinline__ float ftanh(float v){ return 2.f * __builtin_amdgcn_rcpf(1.f + __expf(-2.f*v)) - 1.f; }

__device__ __forceinline__ unsigned short h2b(_Float16 h){ union{_Float16 f; unsigned short u;} c; c.f=h; return c.u; }
__device__ __forceinline__ _Float16 b2h(unsigned short u){ union{_Float16 f; unsigned short u;} c; c.u=u; return c.f; }

__device__ __forceinline__ unsigned packh(float v){
    _Float16 hh = (_Float16)v; _Float16 ll = (_Float16)(v - (float)hh);
    return ((unsigned)h2b(hh) << 16) | (unsigned)h2b(ll);
}

__device__ __forceinline__ void split8(float4 a, float4 b, half8& H, half8& L){
    _Float16 h;
    h=(_Float16)a.x; H[0]=h; L[0]=(_Float16)(a.x-(float)h);
    h=(_Float16)a.y; H[1]=h; L[1]=(_Float16)(a.y-(float)h);
    h=(_Float16)a.z; H[2]=h; L[2]=(_Float16)(a.z-(float)h);
    h=(_Float16)a.w; H[3]=h; L[3]=(_Float16)(a.w-(float)h);
    h=(_Float16)b.x; H[4]=h; L[4]=(_Float16)(b.x-(float)h);
    h=(_Float16)b.y; H[5]=h; L[5]=(_Float16)(b.y-(float)h);
    h=(_Float16)b.z; H[6]=h; L[6]=(_Float16)(b.z-(float)h);
    h=(_Float16)b.w; H[7]=h; L[7]=(_Float16)(b.w-(float)h);
}
__device__ __forceinline__ void unpack8(uint4 a, uint4 b, half8& H, half8& L){
    H[0]=b2h((unsigned short)(a.x>>16)); L[0]=b2h((unsigned short)(a.x&0xffffu));
    H[1]=b2h((unsigned short)(a.y>>16)); L[1]=b2h((unsigned short)(a.y&0xffffu));
    H[2]=b2h((unsigned short)(a.z>>16)); L[2]=b2h((unsigned short)(a.z&0xffffu));
    H[3]=b2h((unsigned short)(a.w>>16)); L[3]=b2h((unsigned short)(a.w&0xffffu));
    H[4]=b2h((unsigned short)(b.x>>16)); L[4]=b2h((unsigned short)(b.x&0xffffu));
    H[5]=b2h((unsigned short)(b.y>>16)); L[5]=b2h((unsigned short)(b.y&0xffffu));
    H[6]=b2h((unsigned short)(b.z>>16)); L[6]=b2h((unsigned short)(b.z&0xffffu));
    H[7]=b2h((unsigned short)(b.w>>16)); L[7]=b2h((unsigned short)(b.w&0xffffu));
}

// B fragment -> registers (literal indices only; no dynamic vector indexing)
#define LDBE(e) { int r = kt*32 + quad*8 + (e); \
    float v = (r < R0) ? Wa[r*256 + col] : Wb[(r-R0)*256 + col]; \
    _Float16 hh = (_Float16)v; H[e] = hh; L[e] = (_Float16)(v - (float)hh); }
__device__ __forceinline__ void loadB(const float* __restrict__ Wa, const float* __restrict__ Wb,
                                      int R0, int kt, int quad, int col, half8& H, half8& L){
    LDBE(0) LDBE(1) LDBE(2) LDBE(3) LDBE(4) LDBE(5) LDBE(6) LDBE(7)
}

#define K3(ah_, al_, Bh_, Bl_, acc_) { \
    acc_ = MFMA16(ah_, Bh_, acc_); acc_ = MFMA16(al_, Bh_, acc_); acc_ = MFMA16(ah_, Bl_, acc_); }

#define WRC2(acc_, rowbase, nt_) { int _b=(rowbase)*SGP + (nt_)*16 + ln; \
    sG[_b]=(acc_).x; sG[_b+SGP]=(acc_).y; sG[_b+2*SGP]=(acc_).z; sG[_b+3*SGP]=(acc_).w; }

// read one packed h fragment (rows rbase+ln, k cols kq8..kq8+7) from packed buffer
#define RDHFRAG(buf, rbase, kq8, Hn, Ln) { \
    const unsigned* _p = (buf) + ((rbase)+ln)*SHP + (kq8); \
    uint4 _a = *(const uint4*)_p, _b = *(const uint4*)(_p+4); \
    unpack8(_a,_b,Hn,Ln); }

// ================= FUSED 2-layer LSTM =================
// block 512 = 8 waves, 32 seqs. L0: wave wv -> n-tiles {2wv,2wv+1}, both m-tiles, sG epilogue.
// L1: wave wv -> m-tile wv>>2, n-tiles {j,j+4,j+8,j+12} (j=wv&3) = gates i,f,g,o of cols
// j*16..+15 -> IN-REGISTER epilogue (no sG round-trip). 3 barriers/timestep; sH1 double-buffered.
// h stored packed (f16 hi<<16|lo) -> frag rebuild is shift/mask, not cvt (round-6 VALU fix).
__global__ __launch_bounds__(512, 2) void k_lstm_fused(
    const float* __restrict__ x,
    const float* __restrict__ Wih0, const float* __restrict__ Whh0,
    const float* __restrict__ bih0, const float* __restrict__ bhh0,
    const float* __restrict__ Wih1, const float* __restrict__ Whh1,
    const float* __restrict__ bih1, const float* __restrict__ bhh1,
    float* __restrict__ h1last)
{
    __shared__ float    sG[32 * SGP];       // 33.3 KB (L0 gates only)
    __shared__ unsigned sH0u[32 * SHP];     // 8.7 KB packed h0
    __shared__ unsigned sH1u[2][32 * SHP];  // 17.4 KB packed h1, double-buffered

    const int tid = threadIdx.x, lane = tid & 63, wv = tid >> 6;
    const int quad = lane >> 4, ln = lane & 15;
    const int nt0 = wv * 2, nt1 = wv * 2 + 1;      // L0 n-tiles
    const int mt16 = (wv >> 2) * 16;               // L1 m-tile base row
    const int j1 = wv & 3, jc = j1 * 16 + ln;      // L1 hidden col
    const int k = tid & 63, sg = tid >> 6;
    const int n0 = blockIdx.x * 32;

    // ---- L0 weights: 3 kt x {A,B} x {hi,lo} = 12 half8 (48 VGPR) ----
    half8 p0ah,p0al,p0bh,p0bl, p1ah,p1al,p1bh,p1bl, p2ah,p2al,p2bh,p2bl;
    {
        int colA = nt0*16 + ln, colB = nt1*16 + ln;
        loadB(Wih0,Whh0,32,0,quad,colA,p0ah,p0al); loadB(Wih0,Whh0,32,0,quad,colB,p0bh,p0bl);
        loadB(Wih0,Whh0,32,1,quad,colA,p1ah,p1al); loadB(Wih0,Whh0,32,1,quad,colB,p1bh,p1bl);
        loadB(Wih0,Whh0,32,2,quad,colA,p2ah,p2al); loadB(Wih0,Whh0,32,2,quad,colB,p2bh,p2bl);
    }
    // ---- L1 weights: 4 kt x 4 gates x {hi,lo} = 32 half8 (128 VGPR) ----
    half8 qh00,ql00,qh01,ql01,qh02,ql02,qh03,ql03;
    half8 qh10,ql10,qh11,ql11,qh12,ql12,qh13,ql13;
    half8 qh20,ql20,qh21,ql21,qh22,ql22,qh23,ql23;
    half8 qh30,ql30,qh31,ql31,qh32,ql32,qh33,ql33;
    {
        int cI = jc, cF = 64 + jc, cG = 128 + jc, cO = 192 + jc;
        loadB(Wih1,Whh1,64,0,quad,cI,qh00,ql00); loadB(Wih1,Whh1,64,0,quad,cF,qh01,ql01);
        loadB(Wih1,Whh1,64,0,quad,cG,qh02,ql02); loadB(Wih1,Whh1,64,0,quad,cO,qh03,ql03);
        loadB(Wih1,Whh1,64,1,quad,cI,qh10,ql10); loadB(Wih1,Whh1,64,1,quad,cF,qh11,ql11);
        loadB(Wih1,Whh1,64,1,quad,cG,qh12,ql12); loadB(Wih1,Whh1,64,1,quad,cO,qh13,ql13);
        loadB(Wih1,Whh1,64,2,quad,cI,qh20,ql20); loadB(Wih1,Whh1,64,2,quad,cF,qh21,ql21);
        loadB(Wih1,Whh1,64,2,quad,cG,qh22,ql22); loadB(Wih1,Whh1,64,2,quad,cO,qh23,ql23);
        loadB(Wih1,Whh1,64,3,quad,cI,qh30,ql30); loadB(Wih1,Whh1,64,3,quad,cF,qh31,ql31);
        loadB(Wih1,Whh1,64,3,quad,cG,qh32,ql32); loadB(Wih1,Whh1,64,3,quad,cO,qh33,ql33);
    }
    const float bb0A = bih0[nt0*16+ln] + bhh0[nt0*16+ln];
    const float bb0B = bih0[nt1*16+ln] + bhh0[nt1*16+ln];
    const float bI = bih1[jc] + bhh1[jc];
    const float bF = bih1[64+jc] + bhh1[64+jc];
    const float bGv = bih1[128+jc] + bhh1[128+jc];
    const float bO = bih1[192+jc] + bhh1[192+jc];

    float c00=0.f,c01=0.f,c02=0.f,c03=0.f;          // L0 cell (mapping sg,k)
    float c1a=0.f,c1b=0.f,c1c=0.f,c1d=0.f;          // L1 cell (rows mt16+quad*4+r, col jc)
    for (int idx = tid; idx < 32*SHP; idx += 512) { sH0u[idx] = 0u; sH1u[0][idx] = 0u; }
    __syncthreads();

    #pragma unroll 1
    for (int tt = 0; tt < Tt; ++tt) {
        const unsigned* h1r = sH1u[tt & 1];
        unsigned*       h1w = sH1u[(tt & 1) ^ 1];

        // ---- L0: A-frags = x_t (global, split) + h0_{t-1} (packed LDS, unpack) ----
        const float* xr0 = x + (size_t)(n0+ln)    * (Tt*INP) + tt*INP + quad*8;
        const float* xr1 = x + (size_t)(n0+16+ln) * (Tt*INP) + tt*INP + quad*8;
        float4 xa0 = *(const float4*)xr0, xb0 = *(const float4*)(xr0+4);
        float4 xa1 = *(const float4*)xr1, xb1 = *(const float4*)(xr1+4);
        half8 xf0h,xf0l,xf1h,xf1l;
        split8(xa0,xb0,xf0h,xf0l); split8(xa1,xb1,xf1h,xf1l);
        half8 h00h,h00l,h01h,h01l,h10h,h10l,h11h,h11l;
        RDHFRAG(sH0u, 0,  quad*8,      h00h,h00l)   // mt0, kgrp0
        RDHFRAG(sH0u, 16, quad*8,      h01h,h01l)   // mt1, kgrp0
        RDHFRAG(sH0u, 0,  32 + quad*8, h10h,h10l)   // mt0, kgrp1
        RDHFRAG(sH0u, 16, 32 + quad*8, h11h,h11l)   // mt1, kgrp1
        {
            f4 accA0 = {bb0A,bb0A,bb0A,bb0A}, accA1 = {bb0B,bb0B,bb0B,bb0B};
            f4 accB0 = {bb0A,bb0A,bb0A,bb0A}, accB1 = {bb0B,bb0B,bb0B,bb0B};
            K3(xf0h,xf0l,p0ah,p0al,accA0) K3(xf0h,xf0l,p0bh,p0bl,accA1)
            K3(xf1h,xf1l,p0ah,p0al,accB0) K3(xf1h,xf1l,p0bh,p0bl,accB1)
            K3(h00h,h00l,p1ah,p1al,accA0) K3(h00h,h00l,p1bh,p1bl,accA1)
            K3(h01h,h01l,p1ah,p1al,accB0) K3(h01h,h01l,p1bh,p1bl,accB1)
            K3(h10h,h10l,p2ah,p2al,accA0) K3(h10h,h10l,p2bh,p2bl,accA1)
            K3(h11h,h11l,p2ah,p2al,accB0) K3(h11h,h11l,p2bh,p2bl,accB1)
            WRC2(accA0, quad*4,      nt0)  WRC2(accA1, quad*4,      nt1)
            WRC2(accB0, 16 + quad*4, nt0)  WRC2(accB1, 16 + quad*4, nt1)
        }
        __syncthreads();   // B1: sG visible; sH0 reads done

        // ---- L0 epilogue (sG path), write packed h0_t ----
        #define GE0(ss, creg) { int _b = (ss)*SGP + k; \
            float iv=fsigm(sG[_b]), fv=fsigm(sG[_b+64]); \
            float gv=ftanh(sG[_b+128]), ov=fsigm(sG[_b+192]); \
            creg = fv*creg + iv*gv; sH0u[(ss)*SHP + k] = packh(ov*ftanh(creg)); }
        GE0(sg, c00) GE0(sg+8, c01) GE0(sg+16, c02) GE0(sg+24, c03)
        #undef GE0
        __syncthreads();   // B2: sH0(h0_t) visible; sG reads done

        // ---- L1: A-frags (own m-tile only) + in-register epilogue ----
        half8 a0h,a0l,a1h,a1l,b0h,b0l,b1h,b1l;
        RDHFRAG(sH0u, mt16, quad*8,      a0h,a0l)   // h0_t kgrp0
        RDHFRAG(sH0u, mt16, 32 + quad*8, a1h,a1l)   // h0_t kgrp1
        RDHFRAG(h1r,  mt16, quad*8,      b0h,b0l)   // h1_{t-1} kgrp0
        RDHFRAG(h1r,  mt16, 32 + quad*8, b1h,b1l)   // h1_{t-1} kgrp1
        {
            f4 accI = {bI,bI,bI,bI}, accF = {bF,bF,bF,bF};
            f4 accG = {bGv,bGv,bGv,bGv}, accO = {bO,bO,bO,bO};
            K3(a0h,a0l,qh00,ql00,accI) K3(a0h,a0l,qh01,ql01,accF)
            K3(a0h,a0l,qh02,ql02,accG) K3(a0h,a0l,qh03,ql03,accO)
            K3(a1h,a1l,qh10,ql10,accI) K3(a1h,a1l,qh11,ql11,accF)
            K3(a1h,a1l,qh12,ql12,accG) K3(a1h,a1l,qh13,ql13,accO)
            K3(b0h,b0l,qh20,ql20,accI) K3(b0h,b0l,qh21,ql21,accF)
            K3(b0h,b0l,qh22,ql22,accG) K3(b0h,b0l,qh23,ql23,accO)
            K3(b1h,b1l,qh30,ql30,accI) K3(b1h,b1l,qh31,ql31,accF)
            K3(b1h,b1l,qh32,ql32,accG) K3(b1h,b1l,qh33,ql33,accO)

            #define EPI1(r, gi, gf, gg, go, creg) { \
                float iv=fsigm(gi), fv=fsigm(gf), gv=ftanh(gg), ov=fsigm(go); \
                creg = fv*creg + iv*gv; float hv = ov*ftanh(creg); \
                h1w[(mt16 + quad*4 + (r))*SHP + jc] = packh(hv); \
                if (tt == Tt-1) h1last[(size_t)(n0 + mt16 + quad*4 + (r))*HID + jc] = hv; }
            EPI1(0, accI.x, accF.x, accG.x, accO.x, c1a)
            EPI1(1, accI.y, accF.y, accG.y, accO.y, c1b)
            EPI1(2, accI.z, accF.z, accG.z, accO.z, c1c)
            EPI1(3, accI.w, accF.w, accG.w, accO.w, c1d)
            #undef EPI1
        }
        __syncthreads();   // B3: h1w visible for next ts; sH0/h1r reads done
    }
}

// ---------------- GAT1 projection ----------------
__global__ __launch_bounds__(256) void k_gproj1(
    const float* __restrict__ hl, const float* __restrict__ W1,
    const float* __restrict__ as1, const float* __restrict__ ad1,
    float* __restrict__ H1, float* __restrict__ a_s, float* __restrict__ a_d)
{
    __shared__ float sh[64];
    const int n = blockIdx.x, tid = threadIdx.x;
    if (tid < 64) sh[tid] = hl[(size_t)n * 64 + tid];
    __syncthreads();
    float acc = 0.f;
    #pragma unroll 8
    for (int j = 0; j < 64; ++j) acc += sh[j] * W1[j * 256 + tid];
    H1[(size_t)n * 256 + tid] = acc;
    float ls = acc * as1[tid], ld = acc * ad1[tid];
    #pragma unroll
    for (int off = 32; off >= 1; off >>= 1) { ls += __shfl_down(ls, off); ld += __shfl_down(ld, off); }
    if ((tid & 63) == 0) { a_s[n * 4 + (tid >> 6)] = ls; a_d[n * 4 + (tid >> 6)] = ld; }
}

// ---------------- GAT2 projection ----------------
__global__ __launch_bounds__(256) void k_gproj2(
    const float* __restrict__ h2, const float* __restrict__ W2,
    const float* __restrict__ as2, const float* __restrict__ ad2,
    float* __restrict__ H2, float* __restrict__ a2s, float* __restrict__ a2d)
{
    __shared__ float sh2[4][256];
    const int tid = threadIdx.x;
    const int n0 = blockIdx.x * 4;
    for (int idx = tid; idx < 1024; idx += 256)
        sh2[idx >> 8][idx & 255] = h2[(size_t)(n0 + (idx >> 8)) * 256 + (idx & 255)];
    __syncthreads();
    int w = tid >> 6, L = tid & 63, c = L & 31, half = L >> 5;
    float acc = 0.f;
    #pragma unroll 8
    for (int j = 0; j < 128; ++j) acc += sh2[w][half * 128 + j] * W2[(half * 128 + j) * 32 + c];
    acc += __shfl_down(acc, 32);
    float ls = 0.f, ld = 0.f;
    if (L < 32) {
        H2[(size_t)(n0 + w) * 32 + c] = acc;
        ls = acc * as2[c]; ld = acc * ad2[c];
    }
    #pragma unroll
    for (int off = 16; off >= 1; off >>= 1) { ls += __shfl_down(ls, off); ld += __shfl_down(ld, off); }
    if (L == 0) { a2s[n0 + w] = ls; a2d[n0 + w] = ld; }
}

// ================= edge bucketing (counting sort by dst) =================
__global__ void k_count(const int* __restrict__ ei, int* __restrict__ deg, int E, int Et)
{
    int e = blockIdx.x * blockDim.x + threadIdx.x;
    if (e >= Et) return;
    int d = (e < E) ? ei[E + e] : e - E;
    atomicAdd(&deg[d], 1);
}

__global__ __launch_bounds__(256) void k_scanA(const int* __restrict__ deg, int* __restrict__ off,
                                               int* __restrict__ csum, int N)
{
    __shared__ int sm[256];
    int b = blockIdx.x, tid = threadIdx.x, i = b * 256 + tid;
    int v = (i < N) ? deg[i] : 0;
    sm[tid] = v;
    __syncthreads();
    #pragma unroll
    for (int s = 1; s < 256; s <<= 1) {
        int t = (tid >= s) ? sm[tid - s] : 0;
        __syncthreads();
        sm[tid] += t;
        __syncthreads();
    }
    if (i < N) off[i] = sm[tid] - v;
    if (tid == 255) csum[b] = sm[255];
}

__global__ void k_scanB(int* __restrict__ csum, int NC)
{
    if (blockIdx.x == 0 && threadIdx.x == 0) {
        int run = 0;
        for (int b = 0; b < NC; ++b) { int t = csum[b]; csum[b] = run; run += t; }
    }
}

__global__ __launch_bounds__(256) void k_scanC(int* __restrict__ off, const int* __restrict__ csum, int N)
{
    int i = blockIdx.x * blockDim.x + threadIdx.x;
    if (i < N) off[i] += csum[i >> 8];
}

__global__ void k_fill(const int* __restrict__ ei, int* __restrict__ cursor,
                       int* __restrict__ elist, int E, int Et)
{
    int e = blockIdx.x * blockDim.x + threadIdx.x;
    if (e >= Et) return;
    int s, d;
    if (e < E) { s = ei[e]; d = ei[E + e]; } else { s = d = e - E; }
    int slot = atomicAdd(&cursor[d], 1);
    elist[slot] = s;
}

// ================= GAT1 gather: max+softmax+aggregate+bias+relu fused =================
__global__ __launch_bounds__(256) void k_gat1(
    const int* __restrict__ off, const int* __restrict__ deg, const int* __restrict__ elist,
    const float* __restrict__ a_s, const float* __restrict__ a_d,
    const float* __restrict__ H1, const float* __restrict__ b1,
    float* __restrict__ h2)
{
    __shared__ float sMax[4];
    __shared__ int   sSrc[256];
    __shared__ float sAl[256 * 4];
    const int d = blockIdx.x, tid = threadIdx.x;
    const int h = tid >> 6, ln = tid & 63;
    const int base = off[d], n_e = deg[d];
    const float add = a_d[d * 4 + h];

    float mx = -INFINITY;
    for (int e = ln; e < n_e; e += 64) {
        int s = elist[base + e];
        float a = a_s[s * 4 + h] + add;
        mx = fmaxf(mx, a > 0.f ? a : NEG * a);
    }
    #pragma unroll
    for (int o = 32; o >= 1; o >>= 1) mx = fmaxf(mx, __shfl_down(mx, o));
    if (ln == 0) sMax[h] = mx;
    __syncthreads();

    float acc = 0.f, asum = 0.f;
    for (int c0 = 0; c0 < n_e; c0 += 256) {
        int nc = min(256, n_e - c0);
        if (tid < nc) sSrc[tid] = elist[base + c0 + tid];
        __syncthreads();
        for (int idx = tid; idx < nc * 4; idx += 256) {
            int e = idx >> 2, hh = idx & 3;
            int s = sSrc[e];
            float a = a_s[s * 4 + hh] + a_d[d * 4 + hh];
            float l = a > 0.f ? a : NEG * a;
            sAl[idx] = __expf(l - sMax[hh]);
        }
        __syncthreads();
        for (int e = 0; e < nc; ++e) {
            float al = sAl[e * 4 + h];
            acc  += al * H1[(size_t)sSrc[e] * 256 + tid];
            asum += al;
        }
        __syncthreads();
    }
    float v = acc * __builtin_amdgcn_rcpf(asum) + b1[tid];
    h2[(size_t)d * 256 + tid] = v > 0.f ? v : 0.f;
}

// ================= GAT2 gather =================
__global__ __launch_bounds__(64) void k_gat2(
    const int* __restrict__ off, const int* __restrict__ deg, const int* __restrict__ elist,
    const float* __restrict__ a2s, const float* __restrict__ a2d,
    const float* __restrict__ H2, const float* __restrict__ b2,
    float* __restrict__ outp)
{
    const int d = blockIdx.x, lane = threadIdx.x;
    const int base = off[d], n_e = deg[d];
    const float add = a2d[d];

    float mx = -INFINITY;
    for (int e = lane; e < n_e; e += 64) {
        int s = elist[base + e];
        float a = a2s[s] + add;
        mx = fmaxf(mx, a > 0.f ? a : NEG * a);
    }
    #pragma unroll
    for (int o = 32; o >= 1; o >>= 1) mx = fmaxf(mx, __shfl_down(mx, o));
    mx = __shfl(mx, 0);

    const int half = lane >> 5, c = lane & 31;
    float acc = 0.f, asum = 0.f;
    for (int e = half; e < n_e; e += 2) {
        int s = elist[base + e];
        float a = a2s[s] + add;
        float l = a > 0.f ? a : NEG * a;
        float al = __expf(l - mx);
        acc  += al * H2[(size_t)s * 32 + c];
        asum += al;
    }
    acc  += __shfl_down(acc, 32);
    asum += __shfl_down(asum, 32);
    if (lane < 32) outp[(size_t)d * 32 + c] = acc * __builtin_amdgcn_rcpf(asum) + b2[c];
}

static inline int cdiv(long long a, long long b) { return (int)((a + b - 1) / b); }

extern "C" void kernel_launch(void* const* d_in, const int* in_sizes, int n_in,
                              void* d_out, int out_size, void* d_ws, size_t ws_size,
                              hipStream_t stream)
{
    const float* x    = (const float*)d_in[0];
    const int*   ei   = (const int*)d_in[1];
    const float* Wih0 = (const float*)d_in[2];
    const float* Whh0 = (const float*)d_in[3];
    const float* bih0 = (const float*)d_in[4];
    const float* bhh0 = (const float*)d_in[5];
    const float* Wih1 = (const float*)d_in[6];
    const float* Whh1 = (const float*)d_in[7];
    const float* bih1 = (const float*)d_in[8];
    const float* bhh1 = (const float*)d_in[9];
    const float* W1   = (const float*)d_in[10];
    const float* as1  = (const float*)d_in[11];
    const float* ad1  = (const float*)d_in[12];
    const float* b1   = (const float*)d_in[13];
    const float* W2   = (const float*)d_in[14];
    const float* as2  = (const float*)d_in[15];
    const float* ad2  = (const float*)d_in[16];
    const float* b2   = (const float*)d_in[17];
    float* outp = (float*)d_out;

    const int N  = in_sizes[0] / (Tt * INP);
    const int E  = in_sizes[1] / 2;
    const int Et = E + N;
    const int NC = cdiv(N, 256);

    float* ws = (float*)d_ws;
    float* h1last = ws;                          // N*64
    float* H1   = h1last + (size_t)N * 64;       // N*256
    float* h2   = H1 + (size_t)N * 256;          // N*256
    float* H2   = h2 + (size_t)N * 256;          // N*32
    float* as1p = H2 + (size_t)N * 32;           // N*4
    float* ad1p = as1p + (size_t)N * 4;          // N*4
    float* a2s  = ad1p + (size_t)N * 4;          // N
    float* a2d  = a2s + N;                       // N
    int* deg    = (int*)(a2d + N);               // N
    int* off    = deg + N;                       // N
    int* cursor = off + N;                       // N
    int* csum   = cursor + N;                    // NC
    int* elist  = csum + NC;                     // Et

    // ---- fused 2-layer LSTM ----
    k_lstm_fused<<<dim3(N / 32), dim3(512), 0, stream>>>(
        x, Wih0, Whh0, bih0, bhh0, Wih1, Whh1, bih1, bhh1, h1last);

    // ---- bucket edges by destination ----
    hipMemsetAsync(deg, 0, (size_t)N * 4, stream);
    k_count<<<cdiv(Et, 256), 256, 0, stream>>>(ei, deg, E, Et);
    k_scanA<<<NC, 256, 0, stream>>>(deg, off, csum, N);
    k_scanB<<<1, 1, 0, stream>>>(csum, NC);
    k_scanC<<<NC, 256, 0, stream>>>(off, csum, N);
    hipMemcpyAsync(cursor, off, (size_t)N * 4, hipMemcpyDeviceToDevice, stream);
    k_fill<<<cdiv(Et, 256), 256, 0, stream>>>(ei, cursor, elist, E, Et);

    // ---- GAT layer 1 ----
    k_gproj1<<<dim3(N), dim3(256), 0, stream>>>(h1last, W1, as1, ad1, H1, as1p, ad1p);
    k_gat1<<<dim3(N), dim3(256), 0, stream>>>(off, deg, elist, as1p, ad1p, H1, b1, h2);

    // ---- GAT layer 2 ----
    k_gproj2<<<dim3(N / 4), dim3(256), 0, stream>>>(h2, W2, as2, ad2, H2, a2s, a2d);
    k_gat2<<<dim3(N), dim3(64), 0, stream>>>(off, deg, elist, a2s, a2d, H2, b2, outp);
}

// Round 8
// 714.604 us; speedup vs baseline: 128.9877x; 1.0410x over previous
//
#include <hip/hip_runtime.h>
#include <math.h>

#define Tt  30
#define INP 32
#define HID 64
#define NEG 0.2f
#define SHP 68      // packed-h pitch (uints): +4 pad
#define SGP 260     // sG pitch (floats)

typedef __attribute__((ext_vector_type(8))) _Float16 half8;
typedef __attribute__((ext_vector_type(4))) float    f4;

#define MFMA16(a,b,c) __builtin_amdgcn_mfma_f32_16x16x32_f16((a),(b),(c),0,0,0)

__device__ __forceinline__ float fsigm(float v){ return __builtin_amdgcn_rcpf(1.f + __expf(-v)); }
__device__ __forceinline__ float ftanh(float v){ return 2.f * __builtin_amdgcn_rcpf(1.f + __expf(-2.f*v)) - 1.f; }

__device__ __forceinline__ unsigned short h2b(_Float16 h){ union{_Float16 f; unsigned short u;} c; c.f=h; return c.u; }
__device__ __forceinline__ _Float16 b2h(unsigned short u){ union{_Float16 f; unsigned short u;} c; c.u=u; return c.f; }

__device__ __forceinline__ unsigned packh(float v){
    _Float16 hh = (_Float16)v; _Float16 ll = (_Float16)(v - (float)hh);
    return ((unsigned)h2b(hh) << 16) | (unsigned)h2b(ll);
}

__device__ __forceinline__ void split8(float4 a, float4 b, half8& H, half8& L){
    _Float16 h;
    h=(_Float16)a.x; H[0]=h; L[0]=(_Float16)(a.x-(float)h);
    h=(_Float16)a.y; H[1]=h; L[1]=(_Float16)(a.y-(float)h);
    h=(_Float16)a.z; H[2]=h; L[2]=(_Float16)(a.z-(float)h);
    h=(_Float16)a.w; H[3]=h; L[3]=(_Float16)(a.w-(float)h);
    h=(_Float16)b.x; H[4]=h; L[4]=(_Float16)(b.x-(float)h);
    h=(_Float16)b.y; H[5]=h; L[5]=(_Float16)(b.y-(float)h);
    h=(_Float16)b.z; H[6]=h; L[6]=(_Float16)(b.z-(float)h);
    h=(_Float16)b.w; H[7]=h; L[7]=(_Float16)(b.w-(float)h);
}
__device__ __forceinline__ void unpack8(uint4 a, uint4 b, half8& H, half8& L){
    H[0]=b2h((unsigned short)(a.x>>16)); L[0]=b2h((unsigned short)(a.x&0xffffu));
    H[1]=b2h((unsigned short)(a.y>>16)); L[1]=b2h((unsigned short)(a.y&0xffffu));
    H[2]=b2h((unsigned short)(a.z>>16)); L[2]=b2h((unsigned short)(a.z&0xffffu));
    H[3]=b2h((unsigned short)(a.w>>16)); L[3]=b2h((unsigned short)(a.w&0xffffu));
    H[4]=b2h((unsigned short)(b.x>>16)); L[4]=b2h((unsigned short)(b.x&0xffffu));
    H[5]=b2h((unsigned short)(b.y>>16)); L[5]=b2h((unsigned short)(b.y&0xffffu));
    H[6]=b2h((unsigned short)(b.z>>16)); L[6]=b2h((unsigned short)(b.z&0xffffu));
    H[7]=b2h((unsigned short)(b.w>>16)); L[7]=b2h((unsigned short)(b.w&0xffffu));
}

// B fragment -> registers (literal indices only; no dynamic vector indexing)
#define LDBE(e) { int r = kt*32 + quad*8 + (e); \
    float v = (r < R0) ? Wa[r*256 + col] : Wb[(r-R0)*256 + col]; \
    _Float16 hh = (_Float16)v; H[e] = hh; L[e] = (_Float16)(v - (float)hh); }
__device__ __forceinline__ void loadB(const float* __restrict__ Wa, const float* __restrict__ Wb,
                                      int R0, int kt, int quad, int col, half8& H, half8& L){
    LDBE(0) LDBE(1) LDBE(2) LDBE(3) LDBE(4) LDBE(5) LDBE(6) LDBE(7)
}

#define K3(ah_, al_, Bh_, Bl_, acc_) { \
    acc_ = MFMA16(ah_, Bh_, acc_); acc_ = MFMA16(al_, Bh_, acc_); acc_ = MFMA16(ah_, Bl_, acc_); }

#define WRC2(acc_, rowbase, nt_) { int _b=(rowbase)*SGP + (nt_)*16 + ln; \
    sG[_b]=(acc_).x; sG[_b+SGP]=(acc_).y; sG[_b+2*SGP]=(acc_).z; sG[_b+3*SGP]=(acc_).w; }

#define RDHFRAG(buf, rbase, kq8, Hn, Ln) { \
    const unsigned* _p = (buf) + ((rbase)+ln)*SHP + (kq8); \
    uint4 _a = *(const uint4*)_p, _b = *(const uint4*)(_p+4); \
    unpack8(_a,_b,Hn,Ln); }

// ================= FUSED 2-layer LSTM =================
// block 512 = 8 waves, 32 seqs. L0: wave wv -> n-tiles {2wv,2wv+1}, both m-tiles, sG epilogue.
// L1: wave wv -> m-tile wv>>2, gate n-tiles {j,j+4,j+8,j+12} (j=wv&3) -> in-register epilogue.
// TWO barriers/timestep (B3 proved redundant by hazard trace: every LDS write->read pair has
// B1/B2 between). __launch_bounds__(512,1): the (512,2) variant capped VGPR at 128 (behaved
// like CUDA min-blocks) and spilled the 176-VGPR weight set to scratch (round-7 FETCH/WRITE bump).
__global__ __launch_bounds__(512, 1) void k_lstm_fused(
    const float* __restrict__ x,
    const float* __restrict__ Wih0, const float* __restrict__ Whh0,
    const float* __restrict__ bih0, const float* __restrict__ bhh0,
    const float* __restrict__ Wih1, const float* __restrict__ Whh1,
    const float* __restrict__ bih1, const float* __restrict__ bhh1,
    float* __restrict__ h1last)
{
    __shared__ float    sG[32 * SGP];       // 33.3 KB (L0 gates only)
    __shared__ unsigned sH0u[32 * SHP];     // 8.7 KB packed h0
    __shared__ unsigned sH1u[2][32 * SHP];  // 17.4 KB packed h1, double-buffered

    const int tid = threadIdx.x, lane = tid & 63, wv = tid >> 6;
    const int quad = lane >> 4, ln = lane & 15;
    const int nt0 = wv * 2, nt1 = wv * 2 + 1;      // L0 n-tiles
    const int mt16 = (wv >> 2) * 16;               // L1 m-tile base row
    const int j1 = wv & 3, jc = j1 * 16 + ln;      // L1 hidden col
    const int k = tid & 63, sg = tid >> 6;
    const int n0 = blockIdx.x * 32;

    // ---- L0 weights: 12 half8 (48 VGPR) ----
    half8 p0ah,p0al,p0bh,p0bl, p1ah,p1al,p1bh,p1bl, p2ah,p2al,p2bh,p2bl;
    {
        int colA = nt0*16 + ln, colB = nt1*16 + ln;
        loadB(Wih0,Whh0,32,0,quad,colA,p0ah,p0al); loadB(Wih0,Whh0,32,0,quad,colB,p0bh,p0bl);
        loadB(Wih0,Whh0,32,1,quad,colA,p1ah,p1al); loadB(Wih0,Whh0,32,1,quad,colB,p1bh,p1bl);
        loadB(Wih0,Whh0,32,2,quad,colA,p2ah,p2al); loadB(Wih0,Whh0,32,2,quad,colB,p2bh,p2bl);
    }
    // ---- L1 weights: 32 half8 (128 VGPR) ----
    half8 qh00,ql00,qh01,ql01,qh02,ql02,qh03,ql03;
    half8 qh10,ql10,qh11,ql11,qh12,ql12,qh13,ql13;
    half8 qh20,ql20,qh21,ql21,qh22,ql22,qh23,ql23;
    half8 qh30,ql30,qh31,ql31,qh32,ql32,qh33,ql33;
    {
        int cI = jc, cF = 64 + jc, cG = 128 + jc, cO = 192 + jc;
        loadB(Wih1,Whh1,64,0,quad,cI,qh00,ql00); loadB(Wih1,Whh1,64,0,quad,cF,qh01,ql01);
        loadB(Wih1,Whh1,64,0,quad,cG,qh02,ql02); loadB(Wih1,Whh1,64,0,quad,cO,qh03,ql03);
        loadB(Wih1,Whh1,64,1,quad,cI,qh10,ql10); loadB(Wih1,Whh1,64,1,quad,cF,qh11,ql11);
        loadB(Wih1,Whh1,64,1,quad,cG,qh12,ql12); loadB(Wih1,Whh1,64,1,quad,cO,qh13,ql13);
        loadB(Wih1,Whh1,64,2,quad,cI,qh20,ql20); loadB(Wih1,Whh1,64,2,quad,cF,qh21,ql21);
        loadB(Wih1,Whh1,64,2,quad,cG,qh22,ql22); loadB(Wih1,Whh1,64,2,quad,cO,qh23,ql23);
        loadB(Wih1,Whh1,64,3,quad,cI,qh30,ql30); loadB(Wih1,Whh1,64,3,quad,cF,qh31,ql31);
        loadB(Wih1,Whh1,64,3,quad,cG,qh32,ql32); loadB(Wih1,Whh1,64,3,quad,cO,qh33,ql33);
    }
    const float bb0A = bih0[nt0*16+ln] + bhh0[nt0*16+ln];
    const float bb0B = bih0[nt1*16+ln] + bhh0[nt1*16+ln];
    const float bI = bih1[jc] + bhh1[jc];
    const float bF = bih1[64+jc] + bhh1[64+jc];
    const float bGv = bih1[128+jc] + bhh1[128+jc];
    const float bO = bih1[192+jc] + bhh1[192+jc];

    float c00=0.f,c01=0.f,c02=0.f,c03=0.f;          // L0 cell (mapping sg,k)
    float c1a=0.f,c1b=0.f,c1c=0.f,c1d=0.f;          // L1 cell (rows mt16+quad*4+r, col jc)
    for (int idx = tid; idx < 32*SHP; idx += 512) { sH0u[idx] = 0u; sH1u[0][idx] = 0u; }
    __syncthreads();

    #pragma unroll 1
    for (int tt = 0; tt < Tt; ++tt) {
        const unsigned* h1r = sH1u[tt & 1];
        unsigned*       h1w = sH1u[(tt & 1) ^ 1];

        // ---- L0: A-frags = x_t (global, split) + h0_{t-1} (packed LDS) ----
        const float* xr0 = x + (size_t)(n0+ln)    * (Tt*INP) + tt*INP + quad*8;
        const float* xr1 = x + (size_t)(n0+16+ln) * (Tt*INP) + tt*INP + quad*8;
        float4 xa0 = *(const float4*)xr0, xb0 = *(const float4*)(xr0+4);
        float4 xa1 = *(const float4*)xr1, xb1 = *(const float4*)(xr1+4);
        half8 xf0h,xf0l,xf1h,xf1l;
        split8(xa0,xb0,xf0h,xf0l); split8(xa1,xb1,xf1h,xf1l);
        half8 h00h,h00l,h01h,h01l,h10h,h10l,h11h,h11l;
        RDHFRAG(sH0u, 0,  quad*8,      h00h,h00l)
        RDHFRAG(sH0u, 16, quad*8,      h01h,h01l)
        RDHFRAG(sH0u, 0,  32 + quad*8, h10h,h10l)
        RDHFRAG(sH0u, 16, 32 + quad*8, h11h,h11l)
        {
            f4 accA0 = {bb0A,bb0A,bb0A,bb0A}, accA1 = {bb0B,bb0B,bb0B,bb0B};
            f4 accB0 = {bb0A,bb0A,bb0A,bb0A}, accB1 = {bb0B,bb0B,bb0B,bb0B};
            K3(xf0h,xf0l,p0ah,p0al,accA0) K3(xf0h,xf0l,p0bh,p0bl,accA1)
            K3(xf1h,xf1l,p0ah,p0al,accB0) K3(xf1h,xf1l,p0bh,p0bl,accB1)
            K3(h00h,h00l,p1ah,p1al,accA0) K3(h00h,h00l,p1bh,p1bl,accA1)
            K3(h01h,h01l,p1ah,p1al,accB0) K3(h01h,h01l,p1bh,p1bl,accB1)
            K3(h10h,h10l,p2ah,p2al,accA0) K3(h10h,h10l,p2bh,p2bl,accA1)
            K3(h11h,h11l,p2ah,p2al,accB0) K3(h11h,h11l,p2bh,p2bl,accB1)
            WRC2(accA0, quad*4,      nt0)  WRC2(accA1, quad*4,      nt1)
            WRC2(accB0, 16 + quad*4, nt0)  WRC2(accB1, 16 + quad*4, nt1)
        }
        __syncthreads();   // B1: sG visible; L0 reads of sH0u done

        // ---- L0 epilogue (sG path), write packed h0_t ----
        #define GE0(ss, creg) { int _b = (ss)*SGP + k; \
            float iv=fsigm(sG[_b]), fv=fsigm(sG[_b+64]); \
            float gv=ftanh(sG[_b+128]), ov=fsigm(sG[_b+192]); \
            creg = fv*creg + iv*gv; sH0u[(ss)*SHP + k] = packh(ov*ftanh(creg)); }
        GE0(sg, c00) GE0(sg+8, c01) GE0(sg+16, c02) GE0(sg+24, c03)
        #undef GE0
        __syncthreads();   // B2: sH0(h0_t) visible; sG reads done

        // ---- L1: A-frags (own m-tile) + in-register epilogue ----
        half8 a0h,a0l,a1h,a1l,b0h,b0l,b1h,b1l;
        RDHFRAG(sH0u, mt16, quad*8,      a0h,a0l)
        RDHFRAG(sH0u, mt16, 32 + quad*8, a1h,a1l)
        RDHFRAG(h1r,  mt16, quad*8,      b0h,b0l)
        RDHFRAG(h1r,  mt16, 32 + quad*8, b1h,b1l)
        {
            f4 accI = {bI,bI,bI,bI}, accF = {bF,bF,bF,bF};
            f4 accG = {bGv,bGv,bGv,bGv}, accO = {bO,bO,bO,bO};
            K3(a0h,a0l,qh00,ql00,accI) K3(a0h,a0l,qh01,ql01,accF)
            K3(a0h,a0l,qh02,ql02,accG) K3(a0h,a0l,qh03,ql03,accO)
            K3(a1h,a1l,qh10,ql10,accI) K3(a1h,a1l,qh11,ql11,accF)
            K3(a1h,a1l,qh12,ql12,accG) K3(a1h,a1l,qh13,ql13,accO)
            K3(b0h,b0l,qh20,ql20,accI) K3(b0h,b0l,qh21,ql21,accF)
            K3(b0h,b0l,qh22,ql22,accG) K3(b0h,b0l,qh23,ql23,accO)
            K3(b1h,b1l,qh30,ql30,accI) K3(b1h,b1l,qh31,ql31,accF)
            K3(b1h,b1l,qh32,ql32,accG) K3(b1h,b1l,qh33,ql33,accO)

            #define EPI1(r, gi, gf, gg, go, creg) { \
                float iv=fsigm(gi), fv=fsigm(gf), gv=ftanh(gg), ov=fsigm(go); \
                creg = fv*creg + iv*gv; float hv = ov*ftanh(creg); \
                h1w[(mt16 + quad*4 + (r))*SHP + jc] = packh(hv); \
                if (tt == Tt-1) h1last[(size_t)(n0 + mt16 + quad*4 + (r))*HID + jc] = hv; }
            EPI1(0, accI.x, accF.x, accG.x, accO.x, c1a)
            EPI1(1, accI.y, accF.y, accG.y, accO.y, c1b)
            EPI1(2, accI.z, accF.z, accG.z, accO.z, c1c)
            EPI1(3, accI.w, accF.w, accG.w, accO.w, c1d)
            #undef EPI1
        }
        // no barrier here: h1w(t) reads happen after B2(t+1); sH0u overwrite after B1(t+1)
    }
}

// ---------------- GAT1 projection ----------------
__global__ __launch_bounds__(256) void k_gproj1(
    const float* __restrict__ hl, const float* __restrict__ W1,
    const float* __restrict__ as1, const float* __restrict__ ad1,
    float* __restrict__ H1, float* __restrict__ a_s, float* __restrict__ a_d)
{
    __shared__ float sh[64];
    const int n = blockIdx.x, tid = threadIdx.x;
    if (tid < 64) sh[tid] = hl[(size_t)n * 64 + tid];
    __syncthreads();
    float acc = 0.f;
    #pragma unroll 8
    for (int j = 0; j < 64; ++j) acc += sh[j] * W1[j * 256 + tid];
    H1[(size_t)n * 256 + tid] = acc;
    float ls = acc * as1[tid], ld = acc * ad1[tid];
    #pragma unroll
    for (int off = 32; off >= 1; off >>= 1) { ls += __shfl_down(ls, off); ld += __shfl_down(ld, off); }
    if ((tid & 63) == 0) { a_s[n * 4 + (tid >> 6)] = ls; a_d[n * 4 + (tid >> 6)] = ld; }
}

// ---------------- GAT2 projection ----------------
__global__ __launch_bounds__(256) void k_gproj2(
    const float* __restrict__ h2, const float* __restrict__ W2,
    const float* __restrict__ as2, const float* __restrict__ ad2,
    float* __restrict__ H2, float* __restrict__ a2s, float* __restrict__ a2d)
{
    __shared__ float sh2[4][256];
    const int tid = threadIdx.x;
    const int n0 = blockIdx.x * 4;
    for (int idx = tid; idx < 1024; idx += 256)
        sh2[idx >> 8][idx & 255] = h2[(size_t)(n0 + (idx >> 8)) * 256 + (idx & 255)];
    __syncthreads();
    int w = tid >> 6, L = tid & 63, c = L & 31, half = L >> 5;
    float acc = 0.f;
    #pragma unroll 8
    for (int j = 0; j < 128; ++j) acc += sh2[w][half * 128 + j] * W2[(half * 128 + j) * 32 + c];
    acc += __shfl_down(acc, 32);
    float ls = 0.f, ld = 0.f;
    if (L < 32) {
        H2[(size_t)(n0 + w) * 32 + c] = acc;
        ls = acc * as2[c]; ld = acc * ad2[c];
    }
    #pragma unroll
    for (int off = 16; off >= 1; off >>= 1) { ls += __shfl_down(ls, off); ld += __shfl_down(ld, off); }
    if (L == 0) { a2s[n0 + w] = ls; a2d[n0 + w] = ld; }
}

// ================= edge bucketing (counting sort by dst) =================
__global__ void k_count(const int* __restrict__ ei, int* __restrict__ deg, int E, int Et)
{
    int e = blockIdx.x * blockDim.x + threadIdx.x;
    if (e >= Et) return;
    int d = (e < E) ? ei[E + e] : e - E;
    atomicAdd(&deg[d], 1);
}

__global__ __launch_bounds__(256) void k_scanA(const int* __restrict__ deg, int* __restrict__ off,
                                               int* __restrict__ csum, int N)
{
    __shared__ int sm[256];
    int b = blockIdx.x, tid = threadIdx.x, i = b * 256 + tid;
    int v = (i < N) ? deg[i] : 0;
    sm[tid] = v;
    __syncthreads();
    #pragma unroll
    for (int s = 1; s < 256; s <<= 1) {
        int t = (tid >= s) ? sm[tid - s] : 0;
        __syncthreads();
        sm[tid] += t;
        __syncthreads();
    }
    if (i < N) off[i] = sm[tid] - v;
    if (tid == 255) csum[b] = sm[255];
}

__global__ void k_scanB(int* __restrict__ csum, int NC)
{
    if (blockIdx.x == 0 && threadIdx.x == 0) {
        int run = 0;
        for (int b = 0; b < NC; ++b) { int t = csum[b]; csum[b] = run; run += t; }
    }
}

__global__ __launch_bounds__(256) void k_scanC(int* __restrict__ off, const int* __restrict__ csum, int N)
{
    int i = blockIdx.x * blockDim.x + threadIdx.x;
    if (i < N) off[i] += csum[i >> 8];
}

__global__ void k_fill(const int* __restrict__ ei, int* __restrict__ cursor,
                       int* __restrict__ elist, int E, int Et)
{
    int e = blockIdx.x * blockDim.x + threadIdx.x;
    if (e >= Et) return;
    int s, d;
    if (e < E) { s = ei[e]; d = ei[E + e]; } else { s = d = e - E; }
    int slot = atomicAdd(&cursor[d], 1);
    elist[slot] = s;
}

// ================= GAT1 gather: max+softmax+aggregate+bias+relu fused =================
__global__ __launch_bounds__(256) void k_gat1(
    const int* __restrict__ off, const int* __restrict__ deg, const int* __restrict__ elist,
    const float* __restrict__ a_s, const float* __restrict__ a_d,
    const float* __restrict__ H1, const float* __restrict__ b1,
    float* __restrict__ h2)
{
    __shared__ float sMax[4];
    __shared__ int   sSrc[256];
    __shared__ float sAl[256 * 4];
    const int d = blockIdx.x, tid = threadIdx.x;
    const int h = tid >> 6, ln = tid & 63;
    const int base = off[d], n_e = deg[d];
    const float add = a_d[d * 4 + h];

    float mx = -INFINITY;
    for (int e = ln; e < n_e; e += 64) {
        int s = elist[base + e];
        float a = a_s[s * 4 + h] + add;
        mx = fmaxf(mx, a > 0.f ? a : NEG * a);
    }
    #pragma unroll
    for (int o = 32; o >= 1; o >>= 1) mx = fmaxf(mx, __shfl_down(mx, o));
    if (ln == 0) sMax[h] = mx;
    __syncthreads();

    float acc = 0.f, asum = 0.f;
    for (int c0 = 0; c0 < n_e; c0 += 256) {
        int nc = min(256, n_e - c0);
        if (tid < nc) sSrc[tid] = elist[base + c0 + tid];
        __syncthreads();
        for (int idx = tid; idx < nc * 4; idx += 256) {
            int e = idx >> 2, hh = idx & 3;
            int s = sSrc[e];
            float a = a_s[s * 4 + hh] + a_d[d * 4 + hh];
            float l = a > 0.f ? a : NEG * a;
            sAl[idx] = __expf(l - sMax[hh]);
        }
        __syncthreads();
        for (int e = 0; e < nc; ++e) {
            float al = sAl[e * 4 + h];
            acc  += al * H1[(size_t)sSrc[e] * 256 + tid];
            asum += al;
        }
        __syncthreads();
    }
    float v = acc * __builtin_amdgcn_rcpf(asum) + b1[tid];
    h2[(size_t)d * 256 + tid] = v > 0.f ? v : 0.f;
}

// ================= GAT2 gather =================
__global__ __launch_bounds__(64) void k_gat2(
    const int* __restrict__ off, const int* __restrict__ deg, const int* __restrict__ elist,
    const float* __restrict__ a2s, const float* __restrict__ a2d,
    const float* __restrict__ H2, const float* __restrict__ b2,
    float* __restrict__ outp)
{
    const int d = blockIdx.x, lane = threadIdx.x;
    const int base = off[d], n_e = deg[d];
    const float add = a2d[d];

    float mx = -INFINITY;
    for (int e = lane; e < n_e; e += 64) {
        int s = elist[base + e];
        float a = a2s[s] + add;
        mx = fmaxf(mx, a > 0.f ? a : NEG * a);
    }
    #pragma unroll
    for (int o = 32; o >= 1; o >>= 1) mx = fmaxf(mx, __shfl_down(mx, o));
    mx = __shfl(mx, 0);

    const int half = lane >> 5, c = lane & 31;
    float acc = 0.f, asum = 0.f;
    for (int e = half; e < n_e; e += 2) {
        int s = elist[base + e];
        float a = a2s[s] + add;
        float l = a > 0.f ? a : NEG * a;
        float al = __expf(l - mx);
        acc  += al * H2[(size_t)s * 32 + c];
        asum += al;
    }
    acc  += __shfl_down(acc, 32);
    asum += __shfl_down(asum, 32);
    if (lane < 32) outp[(size_t)d * 32 + c] = acc * __builtin_amdgcn_rcpf(asum) + b2[c];
}

static inline int cdiv(long long a, long long b) { return (int)((a + b - 1) / b); }

extern "C" void kernel_launch(void* const* d_in, const int* in_sizes, int n_in,
                              void* d_out, int out_size, void* d_ws, size_t ws_size,
                              hipStream_t stream)
{
    const float* x    = (const float*)d_in[0];
    const int*   ei   = (const int*)d_in[1];
    const float* Wih0 = (const float*)d_in[2];
    const float* Whh0 = (const float*)d_in[3];
    const float* bih0 = (const float*)d_in[4];
    const float* bhh0 = (const float*)d_in[5];
    const float* Wih1 = (const float*)d_in[6];
    const float* Whh1 = (const float*)d_in[7];
    const float* bih1 = (const float*)d_in[8];
    const float* bhh1 = (const float*)d_in[9];
    const float* W1   = (const float*)d_in[10];
    const float* as1  = (const float*)d_in[11];
    const float* ad1  = (const float*)d_in[12];
    const float* b1   = (const float*)d_in[13];
    const float* W2   = (const float*)d_in[14];
    const float* as2  = (const float*)d_in[15];
    const float* ad2  = (const float*)d_in[16];
    const float* b2   = (const float*)d_in[17];
    float* outp = (float*)d_out;

    const int N  = in_sizes[0] / (Tt * INP);
    const int E  = in_sizes[1] / 2;
    const int Et = E + N;
    const int NC = cdiv(N, 256);

    float* ws = (float*)d_ws;
    float* h1last = ws;                          // N*64
    float* H1   = h1last + (size_t)N * 64;       // N*256
    float* h2   = H1 + (size_t)N * 256;          // N*256
    float* H2   = h2 + (size_t)N * 256;          // N*32
    float* as1p = H2 + (size_t)N * 32;           // N*4
    float* ad1p = as1p + (size_t)N * 4;          // N*4
    float* a2s  = ad1p + (size_t)N * 4;          // N
    float* a2d  = a2s + N;                       // N
    int* deg    = (int*)(a2d + N);               // N
    int* off    = deg + N;                       // N
    int* cursor = off + N;                       // N
    int* csum   = cursor + N;                    // NC
    int* elist  = csum + NC;                     // Et

    // ---- fused 2-layer LSTM ----
    k_lstm_fused<<<dim3(N / 32), dim3(512), 0, stream>>>(
        x, Wih0, Whh0, bih0, bhh0, Wih1, Whh1, bih1, bhh1, h1last);

    // ---- bucket edges by destination ----
    hipMemsetAsync(deg, 0, (size_t)N * 4, stream);
    k_count<<<cdiv(Et, 256), 256, 0, stream>>>(ei, deg, E, Et);
    k_scanA<<<NC, 256, 0, stream>>>(deg, off, csum, N);
    k_scanB<<<1, 1, 0, stream>>>(csum, NC);
    k_scanC<<<NC, 256, 0, stream>>>(off, csum, N);
    hipMemcpyAsync(cursor, off, (size_t)N * 4, hipMemcpyDeviceToDevice, stream);
    k_fill<<<cdiv(Et, 256), 256, 0, stream>>>(ei, cursor, elist, E, Et);

    // ---- GAT layer 1 ----
    k_gproj1<<<dim3(N), dim3(256), 0, stream>>>(h1last, W1, as1, ad1, H1, as1p, ad1p);
    k_gat1<<<dim3(N), dim3(256), 0, stream>>>(off, deg, elist, as1p, ad1p, H1, b1, h2);

    // ---- GAT layer 2 ----
    k_gproj2<<<dim3(N / 4), dim3(256), 0, stream>>>(h2, W2, as2, ad2, H2, a2s, a2d);
    k_gat2<<<dim3(N), dim3(64), 0, stream>>>(off, deg, elist, a2s, a2d, H2, b2, outp);
}